// Round 5
// baseline (803.917 us; speedup 1.0000x reference)
//
#include <hip/hip_runtime.h>
#include <hip/hip_fp16.h>
#include <math.h>

typedef unsigned short u16;
typedef __attribute__((ext_vector_type(8))) short bf16x8;   // 8 bf16 = 4 VGPR
typedef __attribute__((ext_vector_type(4))) float f32x4;

constexpr int B_ = 16;
constexpr int D_ = 512;
constexpr int N_ = 2048;
constexpr int S_ = 15;
constexpr int TOPK = 16;

constexpr int BK  = 32;
constexpr int KP  = 2 * D_;           // 1024 packed bf16 per row (hi|lo)
constexpr int BN7 = 256;              // chunk width
constexpr int SCW4 = 68;              // sC row stride for 64-col quarter (16B-aligned)

// async global->LDS, 16 bytes per lane (dest = wave-uniform base + lane*16)
__device__ __forceinline__ void gl_lds16(const void* g, void* s) {
    __builtin_amdgcn_global_load_lds(
        (const __attribute__((address_space(1))) unsigned int*)g,
        (__attribute__((address_space(3))) unsigned int*)s, 16, 0, 0);
}

// fp8 e4m3fn encode of a POSITIVE float (we only encode exp(l) > 0).
__device__ __forceinline__ unsigned enc1(float x) {
    x = fminf(x, 448.f);
    unsigned u = __float_as_uint(x);
    if (u < 0x3C800000u) return 0u;                    // < 2^-6
    unsigned r = u + 0x7FFFFu + ((u >> 20) & 1u);      // rn-even, keep 3 mant bits
    unsigned f = (r >> 20) - 0x3C0u;                   // rebias 127->7
    return f > 0x7Eu ? 0x7Eu : f;
}
__device__ __forceinline__ float dec1(unsigned f) {
    return f ? __uint_as_float((f + 0x3C0u) << 20) : 0.f;
}

// ---------------------------------------------------------------------------
// Pack: fp32 [B][D][N] -> bf16 [B][N][1024] N-major, row = [hi(0..511)|lo].
// ---------------------------------------------------------------------------
__global__ __launch_bounds__(256) void packbf(
    const float* __restrict__ srcE, const float* __restrict__ tgtE,
    u16* __restrict__ srcP, u16* __restrict__ tgtP)
{
    const int t = threadIdx.x;
    const int b = blockIdx.z & 15, sel = blockIdx.z >> 4;
    const float* in = (sel ? tgtE : srcE) + (size_t)b * D_ * N_;
    u16* out = (sel ? tgtP : srcP) + (size_t)b * N_ * KP;
    const int n0 = blockIdx.x * 64, k0 = blockIdx.y * 64;

    __shared__ float T[64][69];

    #pragma unroll
    for (int it = 0; it < 4; it++) {
        int r = it * 16 + (t >> 4);
        int c = (t & 15) * 4;
        float4 v = *(const float4*)&in[(size_t)(k0 + r) * N_ + n0 + c];
        T[c + 0][r] = v.x; T[c + 1][r] = v.y; T[c + 2][r] = v.z; T[c + 3][r] = v.w;
    }
    __syncthreads();

    const int nn = t >> 2, kc = (t & 3) * 16;
    __align__(16) u16 hi[16], lo[16];
    #pragma unroll
    for (int j = 0; j < 16; j++) {
        float x = T[nn][kc + j];
        unsigned u = __float_as_uint(x);
        unsigned hr = u + 0x7fff + ((u >> 16) & 1);
        u16 h = (u16)(hr >> 16);
        float hf = __uint_as_float((unsigned)h << 16);
        float xl = x - hf;
        unsigned ul = __float_as_uint(xl);
        unsigned lr = ul + 0x7fff + ((ul >> 16) & 1);
        hi[j] = h; lo[j] = (u16)(lr >> 16);
    }
    u16* op = out + (size_t)(n0 + nn) * KP + k0 + kc;
    *(int4*)op         = *(int4*)hi;  *(int4*)(op + 8)   = *(int4*)(hi + 8);
    *(int4*)(op + 512) = *(int4*)lo;  *(int4*)(op + 520) = *(int4*)(lo + 8);
}

// ---------------------------------------------------------------------------
// Pass 1: MFMA GEMM -> 1/Z + sorted top-16 (l - logZ), fp8 E dump.
// Grid 256 (16 rowblocks x 16 batches, XCD-chunked), 512 threads.
// K-loop: triple-buffered staging, counted vmcnt (depth-2 prefetch), raw
// barriers. Per-chunk epilogue in 64-col quarters via sC (lgkm-only barriers);
// one vmcnt(0) drain per chunk (e8 stores). Merge reuses dead staging LDS.
// ---------------------------------------------------------------------------
__global__ __launch_bounds__(512, 2) void gemm7(
    const u16* __restrict__ srcP, const u16* __restrict__ tgtP,
    float* __restrict__ rzbuf, float* __restrict__ topv, int* __restrict__ topc,
    unsigned char* __restrict__ e8)       // nullptr -> no dump (thin path)
{
    __shared__ __align__(16) u16 sS[3 * 16384];        // 96 KB staging (3 bufs)
    __shared__ __align__(16) float sC[128 * SCW4];     // 34 KB epilogue quarter

    const int tid = threadIdx.x;
    const int w = tid >> 6, lane = tid & 63;
    const int wr = w >> 2, wc = w & 3;
    const int sr = lane >> 2, q = lane & 3;
    const int bid = blockIdx.x;
    const int swz = (bid & 7) * 32 + (bid >> 3);
    const int b  = swz >> 4;
    const int s0 = (swz & 15) * 128;
    const float scale = 0.044194173824159216f;

    const u16* srcPb = srcP + (size_t)b * N_ * KP;
    const u16* tgtPb = tgtP + (size_t)b * N_ * KP;

    const int sls = ((lane & 3) ^ ((lane >> 3) & 3)) * 8;
    const u16* pAh = srcPb + (size_t)(s0 + w * 16 + (lane >> 2)) * KP + sls;
    const u16* pB  = tgtPb + (size_t)(w * 16 + (lane >> 2)) * KP + sls;
    const int aro = (lane & 15) * BK + (((lane >> 4) ^ ((lane >> 1) & 3)) * 8);

    // global step g in [0,256): chunk g>>5, in-chunk step g&31.
    // step<16 (P): stage Ah,Al,B0h,B1h (4 loads); step>=16 (Q): Ah,B0l,B1l (3).
    auto stageG = [&](int bi, int g) {
        u16* base = &sS[bi * 16384];
        const int st = g & 31;
        const int c0 = (g >> 5) * BN7;
        const int t32 = (st & 15) * BK;
        gl_lds16(pAh + t32, base + w * 512);
        if (st < 16) {
            gl_lds16(pAh + 512 + t32, base + 4096 + w * 512);
            gl_lds16(pB + (size_t)c0 * KP + t32,         base + 8192 + w * 512);
            gl_lds16(pB + (size_t)(c0 + 128) * KP + t32, base + 12288 + w * 512);
        } else {
            gl_lds16(pB + (size_t)c0 * KP + 512 + t32,         base + 8192 + w * 512);
            gl_lds16(pB + (size_t)(c0 + 128) * KP + 512 + t32, base + 12288 + w * 512);
        }
    };

    float z_loc = 0.f;
    float tv[TOPK]; int tc16[TOPK];
    #pragma unroll
    for (int k = 0; k < TOPK; k++) { tv[k] = -1e30f; tc16[k] = 0x7fffffff; }

    stageG(0, 0);
    stageG(1, 1);
    int bi = 0, bi2 = 2;        // g%3 and (g+2)%3

    for (int ch = 0; ch < 8; ch++) {
        f32x4 acc[4][4];
        #pragma unroll
        for (int i = 0; i < 4; i++)
            #pragma unroll
            for (int j = 0; j < 4; j++) acc[i][j] = (f32x4){0.f, 0.f, 0.f, 0.f};

        for (int s = 0; s < 32; s++) {
            const int g = ch * 32 + s;
            // counted wait: drain stage(g), keep stage(g+1) in flight.
            if (g == 255)                 asm volatile("s_waitcnt vmcnt(0)" ::: "memory");
            else if (((g + 1) & 31) < 16) asm volatile("s_waitcnt vmcnt(4)" ::: "memory");
            else                          asm volatile("s_waitcnt vmcnt(3)" ::: "memory");
            __builtin_amdgcn_s_barrier();
            __builtin_amdgcn_sched_barrier(0);
            if (g + 2 < 256) stageG(bi2, g + 2);
            const u16* base = &sS[bi * 16384];
            bf16x8 afr[4], bfr[4];
            #pragma unroll
            for (int j = 0; j < 4; j++)
                bfr[j] = *(const bf16x8*)&base[8192 + wc * 2048 + j * 512 + aro];
            #pragma unroll
            for (int i = 0; i < 4; i++)
                afr[i] = *(const bf16x8*)&base[wr * 2048 + i * 512 + aro];
            #pragma unroll
            for (int i = 0; i < 4; i++)
                #pragma unroll
                for (int j = 0; j < 4; j++)
                    acc[i][j] = __builtin_amdgcn_mfma_f32_16x16x32_bf16(
                        afr[i], bfr[j], acc[i][j], 0, 0, 0);
            if (s < 16) {
                #pragma unroll
                for (int i = 0; i < 4; i++)
                    afr[i] = *(const bf16x8*)&base[4096 + wr * 2048 + i * 512 + aro];
                #pragma unroll
                for (int i = 0; i < 4; i++)
                    #pragma unroll
                    for (int j = 0; j < 4; j++)
                        acc[i][j] = __builtin_amdgcn_mfma_f32_16x16x32_bf16(
                            afr[i], bfr[j], acc[i][j], 0, 0, 0);
            }
            bi  = (bi  == 2) ? 0 : bi + 1;
            bi2 = (bi2 == 2) ? 0 : bi2 + 1;
        }

        // ---- epilogue: 4 quarters of 64 cols through sC (lgkm-only barriers;
        // in-flight next-chunk stages are NOT drained here) ----
        const int c0 = ch * BN7;
        #pragma unroll 1
        for (int h = 0; h < 4; h++) {
            asm volatile("s_waitcnt lgkmcnt(0)" ::: "memory");  // prev reads retired
            __builtin_amdgcn_s_barrier();                        // sC free
            if (wc == h) {
                #pragma unroll
                for (int i = 0; i < 4; i++)
                    #pragma unroll
                    for (int j = 0; j < 4; j++)
                        #pragma unroll
                        for (int r = 0; r < 4; r++)
                            sC[(wr * 64 + i * 16 + (lane >> 4) * 4 + r) * SCW4
                               + j * 16 + (lane & 15)] = acc[i][j][r] * scale;
            }
            asm volatile("s_waitcnt lgkmcnt(0)" ::: "memory");  // writes complete
            __builtin_amdgcn_s_barrier();                        // sC filled
            const float* rowp = &sC[(w * 16 + sr) * SCW4 + q * 16];
            const int cbase = c0 + h * 64 + q * 16;
            unsigned ow0 = 0, ow1 = 0, ow2 = 0, ow3 = 0;
            #pragma unroll
            for (int mi = 0; mi < 4; mi++) {
                float4 v4 = *(const float4*)&rowp[mi * 4];
                const float vv[4] = {v4.x, v4.y, v4.z, v4.w};
                unsigned wb = 0;
                #pragma unroll
                for (int e = 0; e < 4; e++) {
                    float v = vv[e];
                    float ex = __expf(v);
                    z_loc += ex;
                    wb |= enc1(ex) << (8 * e);
                    if (v > tv[15]) {       // sorted-desc insert, stable
                        const int c = cbase + mi * 4 + e;
                        #pragma unroll
                        for (int k = 15; k >= 1; k--) {
                            bool bk  = v > tv[k];
                            bool bk1 = v > tv[k - 1];
                            float sv = bk1 ? tv[k - 1] : v;
                            int   sc = bk1 ? tc16[k - 1] : c;
                            tv[k]   = bk ? sv : tv[k];
                            tc16[k] = bk ? sc : tc16[k];
                        }
                        if (v > tv[0]) { tv[0] = v; tc16[0] = c; }
                    }
                }
                if (mi == 0) ow0 = wb; else if (mi == 1) ow1 = wb;
                else if (mi == 2) ow2 = wb; else ow3 = wb;
            }
            if (e8) {
                const size_t erow = ((size_t)(b * N_ + s0 + w * 16 + sr)) * N_ + cbase;
                *(uint4*)&e8[erow] = make_uint4(ow0, ow1, ow2, ow3);
            }
        }
        // drain e8 stores (and any stage remnants) so k-loop counted waits
        // see only staging loads. ~400cyc once per chunk.
        asm volatile("s_waitcnt vmcnt(0)" ::: "memory");
    }

    // ---- final merge: wave-private slice in (now dead) staging LDS:
    //   per wave 2112 floats: cbw ints [0,1024) | vbw [1024,2048) | zqw [2048,2112)
    float* sCw = (float*)sS + w * 2112;
    int*   cbw = (int*)sCw;
    float* vbw = sCw + 1024;
    float* zqw = sCw + 2048;
    zqw[lane] = z_loc;
    #pragma unroll
    for (int k = 0; k < TOPK; k++) {
        vbw[lane * 16 + k] = tv[k];
        cbw[lane * 16 + k] = tc16[k];
    }
    if (q == 0) {
        float Z = zqw[lane] + zqw[lane + 1] + zqw[lane + 2] + zqw[lane + 3];
        float lz = logf(Z);
        const int grow = s0 + w * 16 + sr;
        rzbuf[b * N_ + grow] = 1.0f / Z;
        float tmin = -1e30f; int tminslot = 0, tmincol = 0x7fffffff;
        #pragma unroll
        for (int k = 0; k < TOPK; k++) { tv[k] = -1e30f; tc16[k] = 0x7fffffff; }
        for (int qq = 0; qq < 4; qq++) {
            #pragma unroll 1
            for (int k = 0; k < TOPK; k++) {
                float v = vbw[(lane + qq) * 16 + k];
                int c = cbw[(lane + qq) * 16 + k];
                bool ins = (v > tmin) || (v == tmin && c < tmincol);
                if (ins) {
                    #pragma unroll
                    for (int k2 = 0; k2 < TOPK; k2++)
                        if (k2 == tminslot) { tv[k2] = v; tc16[k2] = c; }
                    tmin = tv[0]; tmincol = tc16[0]; tminslot = 0;
                    #pragma unroll
                    for (int k2 = 1; k2 < TOPK; k2++) {
                        bool worse = (tv[k2] < tmin) || (tv[k2] == tmin && tc16[k2] > tmincol);
                        if (worse) { tmin = tv[k2]; tmincol = tc16[k2]; tminslot = k2; }
                    }
                }
            }
        }
        unsigned used = 0;
        size_t rowbase = ((size_t)b * N_ + grow) * TOPK;
        for (int o = 0; o < TOPK; o++) {
            float bvv = -1e31f; int bcc = 0x7fffffff; int bk = 0;
            #pragma unroll
            for (int k = 0; k < TOPK; k++) {
                bool u = (used >> k) & 1u;
                bool better = !u && ((tv[k] > bvv) || (tv[k] == bvv && tc16[k] < bcc));
                if (better) { bvv = tv[k]; bcc = tc16[k]; bk = k; }
            }
            used |= 1u << bk;
            topv[rowbase + o] = bvv - lz;
            topc[rowbase + o] = bcc;
        }
    }
}

// ---------------------------------------------------------------------------
// Fat path: colsum[b][t] = sum_s dec(E8[s][t]) * rz[s]. Grid (2,16,16), 256 thr.
// ---------------------------------------------------------------------------
__global__ __launch_bounds__(256) void colsum3(
    const unsigned char* __restrict__ e8, const float* __restrict__ rzbuf,
    float* __restrict__ colsum)
{
    const int b = blockIdx.z, s0 = blockIdx.y * 128, t0 = blockIdx.x * 1024;
    __shared__ float srz[128];
    if (threadIdx.x < 128) srz[threadIdx.x] = rzbuf[b * N_ + s0 + threadIdx.x];
    __syncthreads();
    const int t = t0 + threadIdx.x * 4;
    const unsigned char* p = e8 + ((size_t)(b * N_ + s0)) * N_ + t;
    float a0 = 0.f, a1 = 0.f, a2 = 0.f, a3 = 0.f;
    #pragma unroll 4
    for (int s = 0; s < 128; s++) {
        unsigned v = *(const unsigned*)(p + (size_t)s * N_);
        float r = srz[s];
        a0 += dec1(v & 255u) * r;
        a1 += dec1((v >> 8) & 255u) * r;
        a2 += dec1((v >> 16) & 255u) * r;
        a3 += dec1(v >> 24) * r;
    }
    atomicAdd(&colsum[b * N_ + t + 0], a0);
    atomicAdd(&colsum[b * N_ + t + 1], a1);
    atomicAdd(&colsum[b * N_ + t + 2], a2);
    atomicAdd(&colsum[b * N_ + t + 3], a3);
}

// ---------------------------------------------------------------------------
// Thin fallback (dormant; fat path proven): recompute GEMM for colsum.
// ---------------------------------------------------------------------------
__global__ __launch_bounds__(512, 2) void gemm8(
    const u16* __restrict__ srcP, const u16* __restrict__ tgtP,
    const float* __restrict__ rzbuf, float* __restrict__ colsum)
{
    __shared__ __align__(16) u16 sS[2 * 16384];
    __shared__ float sRZ[128];

    const int tid = threadIdx.x;
    const int w = tid >> 6, lane = tid & 63;
    const int wr = w >> 2, wc = w & 3;
    const int bid = blockIdx.x;
    const int swz = (bid & 7) * 64 + (bid >> 3);
    const int b   = swz >> 5;
    const int rb  = swz & 31;
    const int s0  = (rb & 15) * 128;
    const int cb0 = (rb >> 4) * 1024;
    const float scale = 0.044194173824159216f;

    const u16* srcPb = srcP + (size_t)b * N_ * KP;
    const u16* tgtPb = tgtP + (size_t)b * N_ * KP;

    if (tid < 128) sRZ[tid] = rzbuf[b * N_ + s0 + tid];

    const int sls = ((lane & 3) ^ ((lane >> 3) & 3)) * 8;
    const u16* pAh = srcPb + (size_t)(s0 + w * 16 + (lane >> 2)) * KP + sls;
    const u16* pB  = tgtPb + (size_t)(w * 16 + (lane >> 2)) * KP + sls;
    const int aro = (lane & 15) * BK + (((lane >> 4) ^ ((lane >> 1) & 3)) * 8);

    auto stage = [&](int bi, int s, int c0) {
        u16* base = &sS[bi * 16384];
        const int t32 = (s & 15) * BK;
        gl_lds16(pAh + t32, base + w * 512);
        if (s < 16) {
            gl_lds16(pAh + 512 + t32, base + 4096 + w * 512);
            gl_lds16(pB + (size_t)c0 * KP + t32,         base + 8192 + w * 512);
            gl_lds16(pB + (size_t)(c0 + 128) * KP + t32, base + 12288 + w * 512);
        } else {
            gl_lds16(pB + (size_t)c0 * KP + 512 + t32,         base + 8192 + w * 512);
            gl_lds16(pB + (size_t)(c0 + 128) * KP + 512 + t32, base + 12288 + w * 512);
        }
    };

    stage(0, 0, cb0);

    for (int ch = 0; ch < 4; ch++) {
        const int c0 = cb0 + ch * BN7;
        f32x4 acc[4][4];
        #pragma unroll
        for (int i = 0; i < 4; i++)
            #pragma unroll
            for (int j = 0; j < 4; j++) acc[i][j] = (f32x4){0.f, 0.f, 0.f, 0.f};

        for (int s = 0; s < 32; s++) {
            __syncthreads();
            if (s < 31)      stage((s + 1) & 1, s + 1, c0);
            else if (ch < 3) stage(0, 0, c0 + BN7);
            const u16* base = &sS[(s & 1) * 16384];
            bf16x8 afr[4], bfr[4];
            #pragma unroll
            for (int j = 0; j < 4; j++)
                bfr[j] = *(const bf16x8*)&base[8192 + wc * 2048 + j * 512 + aro];
            #pragma unroll
            for (int i = 0; i < 4; i++)
                afr[i] = *(const bf16x8*)&base[wr * 2048 + i * 512 + aro];
            #pragma unroll
            for (int i = 0; i < 4; i++)
                #pragma unroll
                for (int j = 0; j < 4; j++)
                    acc[i][j] = __builtin_amdgcn_mfma_f32_16x16x32_bf16(
                        afr[i], bfr[j], acc[i][j], 0, 0, 0);
            if (s < 16) {
                #pragma unroll
                for (int i = 0; i < 4; i++)
                    afr[i] = *(const bf16x8*)&base[4096 + wr * 2048 + i * 512 + aro];
                #pragma unroll
                for (int i = 0; i < 4; i++)
                    #pragma unroll
                    for (int j = 0; j < 4; j++)
                        acc[i][j] = __builtin_amdgcn_mfma_f32_16x16x32_bf16(
                            afr[i], bfr[j], acc[i][j], 0, 0, 0);
            }
        }

        #pragma unroll
        for (int j = 0; j < 4; j++) {
            float s = 0.f;
            #pragma unroll
            for (int i = 0; i < 4; i++)
                #pragma unroll
                for (int r = 0; r < 4; r++)
                    s += __expf(acc[i][j][r] * scale)
                         * sRZ[wr * 64 + i * 16 + (lane >> 4) * 4 + r];
            s += __shfl_xor(s, 16);
            s += __shfl_xor(s, 32);
            if (lane < 16)
                atomicAdd(&colsum[b * N_ + c0 + wc * 64 + j * 16 + lane], s);
        }
    }
}

// ---------------------------------------------------------------------------
// Greedy match + finish (unchanged)
// ---------------------------------------------------------------------------
__global__ __launch_bounds__(256) void match2(
    const float* __restrict__ topv, const int* __restrict__ topc,
    int* __restrict__ mrow, int* __restrict__ mcol)
{
    const int b = blockIdx.x, tid = threadIdx.x;
    __shared__ float bv[N_];
    __shared__ int bc[N_];
    __shared__ int sup[16];
    __shared__ float rv[256];
    __shared__ int rr[256];

    for (int r = tid; r < N_; r += 256) {
        bv[r] = topv[((size_t)b * N_ + r) * TOPK];
        bc[r] = topc[((size_t)b * N_ + r) * TOPK];
    }
    __syncthreads();

    for (int it = 0; it < S_; it++) {
        float mv = -1e30f; int mr = 0x7fffffff;
        #pragma unroll
        for (int j = 0; j < 8; j++) {
            int r = tid + j * 256;
            float v = bv[r];
            if (v > mv) { mv = v; mr = r; }
        }
        rv[tid] = mv; rr[tid] = mr;
        __syncthreads();
        for (int off = 128; off; off >>= 1) {
            if (tid < off) {
                float v2 = rv[tid + off];
                if (v2 > rv[tid] || (v2 == rv[tid] && rr[tid + off] < rr[tid])) {
                    rv[tid] = v2; rr[tid] = rr[tid + off];
                }
            }
            __syncthreads();
        }
        if (tid == 0) {
            int R = rr[0]; int C = bc[R];
            mrow[b * S_ + it] = R; mcol[b * S_ + it] = C;
            sup[it] = C;
            bv[R] = -1e30f;
        }
        __syncthreads();
        const int C = sup[it];
        for (int r = tid; r < N_; r += 256) {
            if (bc[r] == C && bv[r] > -1e29f) {
                float nv = -1e30f; int nc = 0x7fffffff;
                const float* tvp = &topv[((size_t)b * N_ + r) * TOPK];
                const int* tcp = &topc[((size_t)b * N_ + r) * TOPK];
                for (int k = 0; k < TOPK; k++) {
                    int c2 = tcp[k];
                    bool bad = false;
                    for (int qq = 0; qq <= it; qq++) bad = bad || (sup[qq] == c2);
                    if (!bad) { nv = tvp[k]; nc = c2; break; }
                }
                bv[r] = nv; bc[r] = nc;
            }
        }
        __syncthreads();
    }
}

__global__ void finish_kernel(const float* __restrict__ src,
                              const float* __restrict__ tgt,
                              const float* __restrict__ colsum,
                              const int* __restrict__ mrow,
                              const int* __restrict__ mcol,
                              float* __restrict__ out)
{
    const int b = blockIdx.x;
    const int tid = threadIdx.x;
    __shared__ float red[256];
    __shared__ float res[6];

    float ls[3] = {0, 0, 0}, lc[3] = {0, 0, 0};
    for (int n = tid; n < N_; n += 256) {
        float cs = colsum[b * N_ + n];
        #pragma unroll
        for (int j = 0; j < 3; j++) {
            ls[j] += src[(size_t)(b * N_ + n) * 3 + j];
            lc[j] += tgt[(size_t)(b * N_ + n) * 3 + j] * cs;
        }
    }
    for (int j = 0; j < 6; j++) {
        red[tid] = (j < 3) ? ls[j] : lc[j - 3];
        __syncthreads();
        for (int off = 128; off; off >>= 1) {
            if (tid < off) red[tid] += red[tid + off];
            __syncthreads();
        }
        if (tid == 0) res[j] = red[0] / (float)N_;
        __syncthreads();
    }

    if (tid == 0) {
        double ps[S_][3], pt[S_][3];
        double ms[3] = {0, 0, 0}, mt[3] = {0, 0, 0};
        for (int s = 0; s < S_; s++) {
            int r = mrow[b * S_ + s], c = mcol[b * S_ + s];
            for (int j = 0; j < 3; j++) {
                ps[s][j] = (double)src[(size_t)(b * N_ + r) * 3 + j];
                pt[s][j] = (double)tgt[(size_t)(b * N_ + c) * 3 + j];
                ms[j] += ps[s][j]; mt[j] += pt[s][j];
            }
        }
        for (int j = 0; j < 3; j++) { ms[j] /= S_; mt[j] /= S_; }
        double H[3][3] = {{0,0,0},{0,0,0},{0,0,0}};
        for (int s = 0; s < S_; s++)
            for (int i = 0; i < 3; i++)
                for (int j = 0; j < 3; j++)
                    H[i][j] += (ps[s][i] - ms[i]) * (pt[s][j] - mt[j]);

        double A[3][3], Vv[3][3] = {{1,0,0},{0,1,0},{0,0,1}};
        for (int i = 0; i < 3; i++)
            for (int j = 0; j < 3; j++) {
                double acc = 0;
                for (int k = 0; k < 3; k++) acc += H[k][i] * H[k][j];
                A[i][j] = acc;
            }
        for (int sweep = 0; sweep < 30; sweep++) {
            double off = fabs(A[0][1]) + fabs(A[0][2]) + fabs(A[1][2]);
            if (off < 1e-30) break;
            for (int pair = 0; pair < 3; pair++) {
                int p = (pair == 2) ? 1 : 0;
                int q = (pair == 0) ? 1 : 2;
                double apq = A[p][q];
                if (fabs(apq) < 1e-300) continue;
                double theta = (A[q][q] - A[p][p]) / (2.0 * apq);
                double tt = ((theta >= 0) ? 1.0 : -1.0) / (fabs(theta) + sqrt(theta * theta + 1.0));
                double cc = 1.0 / sqrt(tt * tt + 1.0);
                double ssn = tt * cc;
                for (int k = 0; k < 3; k++) {
                    double akp = A[k][p], akq = A[k][q];
                    A[k][p] = cc * akp - ssn * akq;
                    A[k][q] = ssn * akp + cc * akq;
                }
                for (int k = 0; k < 3; k++) {
                    double apk = A[p][k], aqk = A[q][k];
                    A[p][k] = cc * apk - ssn * aqk;
                    A[q][k] = ssn * apk + cc * aqk;
                }
                for (int k = 0; k < 3; k++) {
                    double vkp = Vv[k][p], vkq = Vv[k][q];
                    Vv[k][p] = cc * vkp - ssn * vkq;
                    Vv[k][q] = ssn * vkp + cc * vkq;
                }
            }
        }
        double wv[3] = {A[0][0], A[1][1], A[2][2]};
        for (int a = 0; a < 2; a++)
            for (int b2 = a + 1; b2 < 3; b2++)
                if (wv[b2] > wv[a]) {
                    double tw = wv[a]; wv[a] = wv[b2]; wv[b2] = tw;
                    for (int k = 0; k < 3; k++) {
                        double tv_ = Vv[k][a]; Vv[k][a] = Vv[k][b2]; Vv[k][b2] = tv_;
                    }
                }
        double U[3][3];
        for (int k = 0; k < 3; k++) {
            double u[3], nrm = 0;
            for (int i = 0; i < 3; i++) {
                double acc = 0;
                for (int j = 0; j < 3; j++) acc += H[i][j] * Vv[j][k];
                u[i] = acc; nrm += acc * acc;
            }
            nrm = sqrt(nrm);
            if (nrm < 1e-300) nrm = 1e-300;
            for (int i = 0; i < 3; i++) U[i][k] = u[i] / nrm;
        }
        double r[3][3];
        for (int i = 0; i < 3; i++)
            for (int j = 0; j < 3; j++) {
                double acc = 0;
                for (int k = 0; k < 3; k++) acc += Vv[i][k] * U[j][k];
                r[i][j] = acc;
            }
        double det = r[0][0] * (r[1][1] * r[2][2] - r[1][2] * r[2][1])
                   - r[0][1] * (r[1][0] * r[2][2] - r[1][2] * r[2][0])
                   + r[0][2] * (r[1][0] * r[2][1] - r[1][1] * r[2][0]);
        if (det < 0.0) {
            for (int i = 0; i < 3; i++)
                for (int j = 0; j < 3; j++)
                    r[i][j] -= 2.0 * Vv[i][2] * U[j][2];
        }
        double smean[3] = {(double)res[0], (double)res[1], (double)res[2]};
        double cmean[3] = {(double)res[3], (double)res[4], (double)res[5]};
        for (int i = 0; i < 3; i++)
            for (int j = 0; j < 3; j++)
                out[b * 9 + i * 3 + j] = (float)r[i][j];
        for (int i = 0; i < 3; i++) {
            double acc = cmean[i];
            for (int j = 0; j < 3; j++) acc -= r[i][j] * smean[j];
            out[B_ * 9 + b * 3 + i] = (float)acc;
        }
    }
}

// ---------------------------------------------------------------------------
extern "C" void kernel_launch(void* const* d_in, const int* in_sizes, int n_in,
                              void* d_out, int out_size, void* d_ws, size_t ws_size,
                              hipStream_t stream)
{
    const float* srcE = (const float*)d_in[0];
    const float* tgtE = (const float*)d_in[1];
    const float* src  = (const float*)d_in[2];
    const float* tgt  = (const float*)d_in[3];
    float* out = (float*)d_out;
    char* ws = (char*)d_ws;

    const size_t szP  = (size_t)B_ * N_ * KP * sizeof(u16);   // 64 MiB each
    const size_t szE8 = (size_t)B_ * N_ * N_;                 // 64 MiB fp8
    const size_t szStats = (size_t)B_ * N_ * sizeof(float)
                         + (size_t)B_ * N_ * TOPK * sizeof(float)
                         + (size_t)B_ * N_ * TOPK * sizeof(int)
                         + (size_t)B_ * N_ * sizeof(float)
                         + 2048;
    const bool fat = ws_size >= 2 * szP + szE8 + szStats;     // 196.3 MiB (proven)

    u16* srcP = (u16*)ws;
    u16* tgtP = (u16*)(ws + szP);
    unsigned char* e8 = fat ? (unsigned char*)(ws + 2 * szP) : nullptr;
    size_t off = 2 * szP + (fat ? szE8 : 0);
    float* rzbuf  = (float*)(ws + off); off += (size_t)B_ * N_ * sizeof(float);
    float* topv   = (float*)(ws + off); off += (size_t)B_ * N_ * TOPK * sizeof(float);
    int*   topc   = (int*)(ws + off);   off += (size_t)B_ * N_ * TOPK * sizeof(int);
    float* colsum = (float*)(ws + off); off += (size_t)B_ * N_ * sizeof(float);
    int*   mrow   = (int*)(ws + off);   off += 1024;
    int*   mcol   = (int*)(ws + off);

    hipMemsetAsync(colsum, 0, (size_t)B_ * N_ * sizeof(float), stream);

    packbf<<<dim3(N_ / 64, D_ / 64, 2 * B_), 256, 0, stream>>>(srcE, tgtE, srcP, tgtP);
    gemm7<<<dim3(256), 512, 0, stream>>>(srcP, tgtP, rzbuf, topv, topc, e8);
    if (fat)
        colsum3<<<dim3(2, 16, 16), 256, 0, stream>>>(e8, rzbuf, colsum);
    else
        gemm8<<<dim3(512), 512, 0, stream>>>(srcP, tgtP, rzbuf, colsum);
    match2<<<B_, 256, 0, stream>>>(topv, topc, mrow, mcol);
    finish_kernel<<<B_, 256, 0, stream>>>(src, tgt, colsum, mrow, mcol, out);
}

// Round 6
// 723.476 us; speedup vs baseline: 1.1112x; 1.1112x over previous
//
#include <hip/hip_runtime.h>
#include <hip/hip_fp16.h>
#include <math.h>

typedef unsigned short u16;
typedef __attribute__((ext_vector_type(8))) short bf16x8;   // 8 bf16 = 4 VGPR
typedef __attribute__((ext_vector_type(4))) float f32x4;

constexpr int B_ = 16;
constexpr int D_ = 512;
constexpr int N_ = 2048;
constexpr int S_ = 15;
constexpr int TOPK = 16;

constexpr int BK  = 32;
constexpr int KP  = 2 * D_;           // 1024 packed bf16 per row (hi|lo)
constexpr int BN7 = 256;              // chunk width
constexpr int SCW4 = 68;              // sC row stride for 64-col quarter
constexpr int SBUF = 24576;           // u16 per staging buffer (48 KB)

// async global->LDS, 16 bytes per lane (dest = wave-uniform base + lane*16)
__device__ __forceinline__ void gl_lds16(const void* g, void* s) {
    __builtin_amdgcn_global_load_lds(
        (const __attribute__((address_space(1))) unsigned int*)g,
        (__attribute__((address_space(3))) unsigned int*)s, 16, 0, 0);
}

// fp8 e4m3fn encode of a POSITIVE float (we only encode exp(l) > 0).
__device__ __forceinline__ unsigned enc1(float x) {
    x = fminf(x, 448.f);
    unsigned u = __float_as_uint(x);
    if (u < 0x3C800000u) return 0u;                    // < 2^-6
    unsigned r = u + 0x7FFFFu + ((u >> 20) & 1u);      // rn-even, keep 3 mant bits
    unsigned f = (r >> 20) - 0x3C0u;                   // rebias 127->7
    return f > 0x7Eu ? 0x7Eu : f;
}
__device__ __forceinline__ float dec1(unsigned f) {
    return f ? __uint_as_float((f + 0x3C0u) << 20) : 0.f;
}

// ---------------------------------------------------------------------------
// Pack: fp32 [B][D][N] -> bf16 [B][N][1024] N-major, row = [hi(0..511)|lo].
// ---------------------------------------------------------------------------
__global__ __launch_bounds__(256) void packbf(
    const float* __restrict__ srcE, const float* __restrict__ tgtE,
    u16* __restrict__ srcP, u16* __restrict__ tgtP)
{
    const int t = threadIdx.x;
    const int b = blockIdx.z & 15, sel = blockIdx.z >> 4;
    const float* in = (sel ? tgtE : srcE) + (size_t)b * D_ * N_;
    u16* out = (sel ? tgtP : srcP) + (size_t)b * N_ * KP;
    const int n0 = blockIdx.x * 64, k0 = blockIdx.y * 64;

    __shared__ float T[64][69];

    #pragma unroll
    for (int it = 0; it < 4; it++) {
        int r = it * 16 + (t >> 4);
        int c = (t & 15) * 4;
        float4 v = *(const float4*)&in[(size_t)(k0 + r) * N_ + n0 + c];
        T[c + 0][r] = v.x; T[c + 1][r] = v.y; T[c + 2][r] = v.z; T[c + 3][r] = v.w;
    }
    __syncthreads();

    const int nn = t >> 2, kc = (t & 3) * 16;
    __align__(16) u16 hi[16], lo[16];
    #pragma unroll
    for (int j = 0; j < 16; j++) {
        float x = T[nn][kc + j];
        unsigned u = __float_as_uint(x);
        unsigned hr = u + 0x7fff + ((u >> 16) & 1);
        u16 h = (u16)(hr >> 16);
        float hf = __uint_as_float((unsigned)h << 16);
        float xl = x - hf;
        unsigned ul = __float_as_uint(xl);
        unsigned lr = ul + 0x7fff + ((ul >> 16) & 1);
        hi[j] = h; lo[j] = (u16)(lr >> 16);
    }
    u16* op = out + (size_t)(n0 + nn) * KP + k0 + kc;
    *(int4*)op         = *(int4*)hi;  *(int4*)(op + 8)   = *(int4*)(hi + 8);
    *(int4*)(op + 512) = *(int4*)lo;  *(int4*)(op + 520) = *(int4*)(lo + 8);
}

// ---------------------------------------------------------------------------
// Pass 1: MFMA GEMM -> 1/Z + sorted top-16 (l - logZ), fp8 E dump.
// Grid 256 (16 rowblocks x 16 batches, XCD-chunked), 512 threads.
// Merged k-step: each of 16 steps/chunk stages the FULL k-tile
// {Ah,Al,Bh,Bl} (48 KB, 6 gl_lds/wave) and runs all 3 terms
// (AhBh + AlBh + AhBl = 48 MFMA/wave) -> 128 total steps (was 256),
// amortizing the per-step barrier/drain overhead. Proven r4 sync pattern
// (__syncthreads 2-phase, depth-1 prefetch). Quarter epilogue via sC with
// lgkm-only barriers (in-flight next-chunk prefetch NOT drained).
// ---------------------------------------------------------------------------
__global__ __launch_bounds__(512, 2) void gemm7(
    const u16* __restrict__ srcP, const u16* __restrict__ tgtP,
    float* __restrict__ rzbuf, float* __restrict__ topv, int* __restrict__ topc,
    unsigned char* __restrict__ e8)       // nullptr -> no dump (thin path)
{
    __shared__ __align__(16) u16 sS[2 * SBUF];         // 96 KB staging (2 bufs)
    __shared__ __align__(16) float sC[128 * SCW4];     // 34 KB epilogue quarter

    const int tid = threadIdx.x;
    const int w = tid >> 6, lane = tid & 63;
    const int wr = w >> 2, wc = w & 3;
    const int sr = lane >> 2, q = lane & 3;
    const int bid = blockIdx.x;
    const int swz = (bid & 7) * 32 + (bid >> 3);
    const int b  = swz >> 4;
    const int s0 = (swz & 15) * 128;
    const float scale = 0.044194173824159216f;

    const u16* srcPb = srcP + (size_t)b * N_ * KP;
    const u16* tgtPb = tgtP + (size_t)b * N_ * KP;

    // staging: lane -> row base+(lane>>2); phys 16B slot lane&3 holds logical
    // k-slot (lane&3)^((lane>>3)&3); LDS dest = wave base + lane*16B (linear)
    const int sls = ((lane & 3) ^ ((lane >> 3) & 3)) * 8;
    const u16* pAh = srcPb + (size_t)(s0 + w * 16 + (lane >> 2)) * KP + sls;
    const u16* pB  = tgtPb + (size_t)(w * 16 + (lane >> 2)) * KP + sls;
    // fragment read: row = 16i + (l&15), phys slot = (l>>4) ^ ((row>>1)&3)
    const int aro = (lane & 15) * BK + (((lane >> 4) ^ ((lane >> 1) & 3)) * 8);

    // buffer layout (u16): Ah [0,4096) | Al [4096,8192) | Bh [8192,16384)
    //                      | Bl [16384,24576)
    auto stage = [&](int bi, int kt, int c0) {
        u16* base = &sS[bi * SBUF];
        const int t32 = kt * BK;
        gl_lds16(pAh + t32,       base + w * 512);                     // Ah
        gl_lds16(pAh + 512 + t32, base + 4096 + w * 512);              // Al
        gl_lds16(pB + (size_t)c0 * KP + t32,               base + 8192  + w * 512);
        gl_lds16(pB + (size_t)(c0 + 128) * KP + t32,       base + 12288 + w * 512);
        gl_lds16(pB + (size_t)c0 * KP + 512 + t32,         base + 16384 + w * 512);
        gl_lds16(pB + (size_t)(c0 + 128) * KP + 512 + t32, base + 20480 + w * 512);
    };

    float z_loc = 0.f;
    float tv[TOPK]; int tc16[TOPK];
    #pragma unroll
    for (int k = 0; k < TOPK; k++) { tv[k] = -1e30f; tc16[k] = 0x7fffffff; }

    stage(0, 0, 0);

    for (int ch = 0; ch < 8; ch++) {
        const int c0 = ch * BN7;
        f32x4 acc[4][4];
        #pragma unroll
        for (int i = 0; i < 4; i++)
            #pragma unroll
            for (int j = 0; j < 4; j++) acc[i][j] = (f32x4){0.f, 0.f, 0.f, 0.f};

        for (int kt = 0; kt < 16; kt++) {
            __syncthreads();   // buf (kt&1) staged (vmcnt drained) & prev reads done
            if (kt < 15)      stage((kt + 1) & 1, kt + 1, c0);
            else if (ch < 7)  stage(0, 0, c0 + BN7);
            const u16* base = &sS[(kt & 1) * SBUF];
            bf16x8 ah[4], bh[4], tf[4];
            #pragma unroll
            for (int j = 0; j < 4; j++)
                bh[j] = *(const bf16x8*)&base[8192 + wc * 2048 + j * 512 + aro];
            #pragma unroll
            for (int i = 0; i < 4; i++)
                ah[i] = *(const bf16x8*)&base[wr * 2048 + i * 512 + aro];
            #pragma unroll
            for (int i = 0; i < 4; i++)
                #pragma unroll
                for (int j = 0; j < 4; j++)
                    acc[i][j] = __builtin_amdgcn_mfma_f32_16x16x32_bf16(
                        ah[i], bh[j], acc[i][j], 0, 0, 0);
            #pragma unroll
            for (int i = 0; i < 4; i++)
                tf[i] = *(const bf16x8*)&base[4096 + wr * 2048 + i * 512 + aro];
            #pragma unroll
            for (int i = 0; i < 4; i++)
                #pragma unroll
                for (int j = 0; j < 4; j++)
                    acc[i][j] = __builtin_amdgcn_mfma_f32_16x16x32_bf16(
                        tf[i], bh[j], acc[i][j], 0, 0, 0);
            #pragma unroll
            for (int j = 0; j < 4; j++)
                tf[j] = *(const bf16x8*)&base[16384 + wc * 2048 + j * 512 + aro];
            #pragma unroll
            for (int i = 0; i < 4; i++)
                #pragma unroll
                for (int j = 0; j < 4; j++)
                    acc[i][j] = __builtin_amdgcn_mfma_f32_16x16x32_bf16(
                        ah[i], tf[j], acc[i][j], 0, 0, 0);
        }

        // ---- epilogue: 4 quarters of 64 cols through sC (lgkm-only barriers;
        // in-flight next-chunk stage loads are NOT drained here; e8 stores
        // are fire-and-forget and drain at the next k-loop __syncthreads) ----
        #pragma unroll 1
        for (int h = 0; h < 4; h++) {
            asm volatile("s_waitcnt lgkmcnt(0)" ::: "memory");  // prev reads retired
            __builtin_amdgcn_s_barrier();                        // sC free
            if (wc == h) {
                #pragma unroll
                for (int i = 0; i < 4; i++)
                    #pragma unroll
                    for (int j = 0; j < 4; j++)
                        #pragma unroll
                        for (int r = 0; r < 4; r++)
                            sC[(wr * 64 + i * 16 + (lane >> 4) * 4 + r) * SCW4
                               + j * 16 + (lane & 15)] = acc[i][j][r] * scale;
            }
            asm volatile("s_waitcnt lgkmcnt(0)" ::: "memory");  // writes complete
            __builtin_amdgcn_s_barrier();                        // sC filled
            const float* rowp = &sC[(w * 16 + sr) * SCW4 + q * 16];
            const int cbase = c0 + h * 64 + q * 16;
            unsigned ow0 = 0, ow1 = 0, ow2 = 0, ow3 = 0;
            #pragma unroll
            for (int mi = 0; mi < 4; mi++) {
                float4 v4 = *(const float4*)&rowp[mi * 4];
                const float vv[4] = {v4.x, v4.y, v4.z, v4.w};
                unsigned wb = 0;
                #pragma unroll
                for (int e = 0; e < 4; e++) {
                    float v = vv[e];
                    float ex = __expf(v);
                    z_loc += ex;
                    wb |= enc1(ex) << (8 * e);
                    if (v > tv[15]) {       // sorted-desc insert, stable
                        const int c = cbase + mi * 4 + e;
                        #pragma unroll
                        for (int k = 15; k >= 1; k--) {
                            bool bk  = v > tv[k];
                            bool bk1 = v > tv[k - 1];
                            float sv = bk1 ? tv[k - 1] : v;
                            int   sc = bk1 ? tc16[k - 1] : c;
                            tv[k]   = bk ? sv : tv[k];
                            tc16[k] = bk ? sc : tc16[k];
                        }
                        if (v > tv[0]) { tv[0] = v; tc16[0] = c; }
                    }
                }
                if (mi == 0) ow0 = wb; else if (mi == 1) ow1 = wb;
                else if (mi == 2) ow2 = wb; else ow3 = wb;
            }
            if (e8) {
                const size_t erow = ((size_t)(b * N_ + s0 + w * 16 + sr)) * N_ + cbase;
                *(uint4*)&e8[erow] = make_uint4(ow0, ow1, ow2, ow3);
            }
        }
    }

    // ---- final merge: wave-private slice in (now dead) staging LDS ----
    float* sCw = (float*)sS + w * 2112;
    int*   cbw = (int*)sCw;
    float* vbw = sCw + 1024;
    float* zqw = sCw + 2048;
    zqw[lane] = z_loc;
    #pragma unroll
    for (int k = 0; k < TOPK; k++) {
        vbw[lane * 16 + k] = tv[k];
        cbw[lane * 16 + k] = tc16[k];
    }
    if (q == 0) {
        float Z = zqw[lane] + zqw[lane + 1] + zqw[lane + 2] + zqw[lane + 3];
        float lz = logf(Z);
        const int grow = s0 + w * 16 + sr;
        rzbuf[b * N_ + grow] = 1.0f / Z;
        float tmin = -1e30f; int tminslot = 0, tmincol = 0x7fffffff;
        #pragma unroll
        for (int k = 0; k < TOPK; k++) { tv[k] = -1e30f; tc16[k] = 0x7fffffff; }
        for (int qq = 0; qq < 4; qq++) {
            #pragma unroll 1
            for (int k = 0; k < TOPK; k++) {
                float v = vbw[(lane + qq) * 16 + k];
                int c = cbw[(lane + qq) * 16 + k];
                bool ins = (v > tmin) || (v == tmin && c < tmincol);
                if (ins) {
                    #pragma unroll
                    for (int k2 = 0; k2 < TOPK; k2++)
                        if (k2 == tminslot) { tv[k2] = v; tc16[k2] = c; }
                    tmin = tv[0]; tmincol = tc16[0]; tminslot = 0;
                    #pragma unroll
                    for (int k2 = 1; k2 < TOPK; k2++) {
                        bool worse = (tv[k2] < tmin) || (tv[k2] == tmin && tc16[k2] > tmincol);
                        if (worse) { tmin = tv[k2]; tmincol = tc16[k2]; tminslot = k2; }
                    }
                }
            }
        }
        unsigned used = 0;
        size_t rowbase = ((size_t)b * N_ + grow) * TOPK;
        for (int o = 0; o < TOPK; o++) {
            float bvv = -1e31f; int bcc = 0x7fffffff; int bk = 0;
            #pragma unroll
            for (int k = 0; k < TOPK; k++) {
                bool u = (used >> k) & 1u;
                bool better = !u && ((tv[k] > bvv) || (tv[k] == bvv && tc16[k] < bcc));
                if (better) { bvv = tv[k]; bcc = tc16[k]; bk = k; }
            }
            used |= 1u << bk;
            topv[rowbase + o] = bvv - lz;
            topc[rowbase + o] = bcc;
        }
    }
}

// ---------------------------------------------------------------------------
// Fat path: colsum[b][t] = sum_s dec(E8[s][t]) * rz[s]. Grid (2,16,16), 256 thr.
// ---------------------------------------------------------------------------
__global__ __launch_bounds__(256) void colsum3(
    const unsigned char* __restrict__ e8, const float* __restrict__ rzbuf,
    float* __restrict__ colsum)
{
    const int b = blockIdx.z, s0 = blockIdx.y * 128, t0 = blockIdx.x * 1024;
    __shared__ float srz[128];
    if (threadIdx.x < 128) srz[threadIdx.x] = rzbuf[b * N_ + s0 + threadIdx.x];
    __syncthreads();
    const int t = t0 + threadIdx.x * 4;
    const unsigned char* p = e8 + ((size_t)(b * N_ + s0)) * N_ + t;
    float a0 = 0.f, a1 = 0.f, a2 = 0.f, a3 = 0.f;
    #pragma unroll 4
    for (int s = 0; s < 128; s++) {
        unsigned v = *(const unsigned*)(p + (size_t)s * N_);
        float r = srz[s];
        a0 += dec1(v & 255u) * r;
        a1 += dec1((v >> 8) & 255u) * r;
        a2 += dec1((v >> 16) & 255u) * r;
        a3 += dec1(v >> 24) * r;
    }
    atomicAdd(&colsum[b * N_ + t + 0], a0);
    atomicAdd(&colsum[b * N_ + t + 1], a1);
    atomicAdd(&colsum[b * N_ + t + 2], a2);
    atomicAdd(&colsum[b * N_ + t + 3], a3);
}

// ---------------------------------------------------------------------------
// Thin fallback (dormant; fat path proven): recompute GEMM for colsum.
// ---------------------------------------------------------------------------
__global__ __launch_bounds__(512, 2) void gemm8(
    const u16* __restrict__ srcP, const u16* __restrict__ tgtP,
    const float* __restrict__ rzbuf, float* __restrict__ colsum)
{
    __shared__ __align__(16) u16 sS[2 * 16384];
    __shared__ float sRZ[128];

    const int tid = threadIdx.x;
    const int w = tid >> 6, lane = tid & 63;
    const int wr = w >> 2, wc = w & 3;
    const int bid = blockIdx.x;
    const int swz = (bid & 7) * 64 + (bid >> 3);
    const int b   = swz >> 5;
    const int rb  = swz & 31;
    const int s0  = (rb & 15) * 128;
    const int cb0 = (rb >> 4) * 1024;
    const float scale = 0.044194173824159216f;

    const u16* srcPb = srcP + (size_t)b * N_ * KP;
    const u16* tgtPb = tgtP + (size_t)b * N_ * KP;

    if (tid < 128) sRZ[tid] = rzbuf[b * N_ + s0 + tid];

    const int sls = ((lane & 3) ^ ((lane >> 3) & 3)) * 8;
    const u16* pAh = srcPb + (size_t)(s0 + w * 16 + (lane >> 2)) * KP + sls;
    const u16* pB  = tgtPb + (size_t)(w * 16 + (lane >> 2)) * KP + sls;
    const int aro = (lane & 15) * BK + (((lane >> 4) ^ ((lane >> 1) & 3)) * 8);

    auto stage = [&](int bi, int s, int c0) {
        u16* base = &sS[bi * 16384];
        const int t32 = (s & 15) * BK;
        gl_lds16(pAh + t32, base + w * 512);
        if (s < 16) {
            gl_lds16(pAh + 512 + t32, base + 4096 + w * 512);
            gl_lds16(pB + (size_t)c0 * KP + t32,         base + 8192 + w * 512);
            gl_lds16(pB + (size_t)(c0 + 128) * KP + t32, base + 12288 + w * 512);
        } else {
            gl_lds16(pB + (size_t)c0 * KP + 512 + t32,         base + 8192 + w * 512);
            gl_lds16(pB + (size_t)(c0 + 128) * KP + 512 + t32, base + 12288 + w * 512);
        }
    };

    stage(0, 0, cb0);

    for (int ch = 0; ch < 4; ch++) {
        const int c0 = cb0 + ch * BN7;
        f32x4 acc[4][4];
        #pragma unroll
        for (int i = 0; i < 4; i++)
            #pragma unroll
            for (int j = 0; j < 4; j++) acc[i][j] = (f32x4){0.f, 0.f, 0.f, 0.f};

        for (int s = 0; s < 32; s++) {
            __syncthreads();
            if (s < 31)      stage((s + 1) & 1, s + 1, c0);
            else if (ch < 3) stage(0, 0, c0 + BN7);
            const u16* base = &sS[(s & 1) * 16384];
            bf16x8 afr[4], bfr[4];
            #pragma unroll
            for (int j = 0; j < 4; j++)
                bfr[j] = *(const bf16x8*)&base[8192 + wc * 2048 + j * 512 + aro];
            #pragma unroll
            for (int i = 0; i < 4; i++)
                afr[i] = *(const bf16x8*)&base[wr * 2048 + i * 512 + aro];
            #pragma unroll
            for (int i = 0; i < 4; i++)
                #pragma unroll
                for (int j = 0; j < 4; j++)
                    acc[i][j] = __builtin_amdgcn_mfma_f32_16x16x32_bf16(
                        afr[i], bfr[j], acc[i][j], 0, 0, 0);
            if (s < 16) {
                #pragma unroll
                for (int i = 0; i < 4; i++)
                    afr[i] = *(const bf16x8*)&base[4096 + wr * 2048 + i * 512 + aro];
                #pragma unroll
                for (int i = 0; i < 4; i++)
                    #pragma unroll
                    for (int j = 0; j < 4; j++)
                        acc[i][j] = __builtin_amdgcn_mfma_f32_16x16x32_bf16(
                            afr[i], bfr[j], acc[i][j], 0, 0, 0);
            }
        }

        #pragma unroll
        for (int j = 0; j < 4; j++) {
            float s = 0.f;
            #pragma unroll
            for (int i = 0; i < 4; i++)
                #pragma unroll
                for (int r = 0; r < 4; r++)
                    s += __expf(acc[i][j][r] * scale)
                         * sRZ[wr * 64 + i * 16 + (lane >> 4) * 4 + r];
            s += __shfl_xor(s, 16);
            s += __shfl_xor(s, 32);
            if (lane < 16)
                atomicAdd(&colsum[b * N_ + c0 + wc * 64 + j * 16 + lane], s);
        }
    }
}

// ---------------------------------------------------------------------------
// Greedy match + finish (unchanged)
// ---------------------------------------------------------------------------
__global__ __launch_bounds__(256) void match2(
    const float* __restrict__ topv, const int* __restrict__ topc,
    int* __restrict__ mrow, int* __restrict__ mcol)
{
    const int b = blockIdx.x, tid = threadIdx.x;
    __shared__ float bv[N_];
    __shared__ int bc[N_];
    __shared__ int sup[16];
    __shared__ float rv[256];
    __shared__ int rr[256];

    for (int r = tid; r < N_; r += 256) {
        bv[r] = topv[((size_t)b * N_ + r) * TOPK];
        bc[r] = topc[((size_t)b * N_ + r) * TOPK];
    }
    __syncthreads();

    for (int it = 0; it < S_; it++) {
        float mv = -1e30f; int mr = 0x7fffffff;
        #pragma unroll
        for (int j = 0; j < 8; j++) {
            int r = tid + j * 256;
            float v = bv[r];
            if (v > mv) { mv = v; mr = r; }
        }
        rv[tid] = mv; rr[tid] = mr;
        __syncthreads();
        for (int off = 128; off; off >>= 1) {
            if (tid < off) {
                float v2 = rv[tid + off];
                if (v2 > rv[tid] || (v2 == rv[tid] && rr[tid + off] < rr[tid])) {
                    rv[tid] = v2; rr[tid] = rr[tid + off];
                }
            }
            __syncthreads();
        }
        if (tid == 0) {
            int R = rr[0]; int C = bc[R];
            mrow[b * S_ + it] = R; mcol[b * S_ + it] = C;
            sup[it] = C;
            bv[R] = -1e30f;
        }
        __syncthreads();
        const int C = sup[it];
        for (int r = tid; r < N_; r += 256) {
            if (bc[r] == C && bv[r] > -1e29f) {
                float nv = -1e30f; int nc = 0x7fffffff;
                const float* tvp = &topv[((size_t)b * N_ + r) * TOPK];
                const int* tcp = &topc[((size_t)b * N_ + r) * TOPK];
                for (int k = 0; k < TOPK; k++) {
                    int c2 = tcp[k];
                    bool bad = false;
                    for (int qq = 0; qq <= it; qq++) bad = bad || (sup[qq] == c2);
                    if (!bad) { nv = tvp[k]; nc = c2; break; }
                }
                bv[r] = nv; bc[r] = nc;
            }
        }
        __syncthreads();
    }
}

__global__ void finish_kernel(const float* __restrict__ src,
                              const float* __restrict__ tgt,
                              const float* __restrict__ colsum,
                              const int* __restrict__ mrow,
                              const int* __restrict__ mcol,
                              float* __restrict__ out)
{
    const int b = blockIdx.x;
    const int tid = threadIdx.x;
    __shared__ float red[256];
    __shared__ float res[6];

    float ls[3] = {0, 0, 0}, lc[3] = {0, 0, 0};
    for (int n = tid; n < N_; n += 256) {
        float cs = colsum[b * N_ + n];
        #pragma unroll
        for (int j = 0; j < 3; j++) {
            ls[j] += src[(size_t)(b * N_ + n) * 3 + j];
            lc[j] += tgt[(size_t)(b * N_ + n) * 3 + j] * cs;
        }
    }
    for (int j = 0; j < 6; j++) {
        red[tid] = (j < 3) ? ls[j] : lc[j - 3];
        __syncthreads();
        for (int off = 128; off; off >>= 1) {
            if (tid < off) red[tid] += red[tid + off];
            __syncthreads();
        }
        if (tid == 0) res[j] = red[0] / (float)N_;
        __syncthreads();
    }

    if (tid == 0) {
        double ps[S_][3], pt[S_][3];
        double ms[3] = {0, 0, 0}, mt[3] = {0, 0, 0};
        for (int s = 0; s < S_; s++) {
            int r = mrow[b * S_ + s], c = mcol[b * S_ + s];
            for (int j = 0; j < 3; j++) {
                ps[s][j] = (double)src[(size_t)(b * N_ + r) * 3 + j];
                pt[s][j] = (double)tgt[(size_t)(b * N_ + c) * 3 + j];
                ms[j] += ps[s][j]; mt[j] += pt[s][j];
            }
        }
        for (int j = 0; j < 3; j++) { ms[j] /= S_; mt[j] /= S_; }
        double H[3][3] = {{0,0,0},{0,0,0},{0,0,0}};
        for (int s = 0; s < S_; s++)
            for (int i = 0; i < 3; i++)
                for (int j = 0; j < 3; j++)
                    H[i][j] += (ps[s][i] - ms[i]) * (pt[s][j] - mt[j]);

        double A[3][3], Vv[3][3] = {{1,0,0},{0,1,0},{0,0,1}};
        for (int i = 0; i < 3; i++)
            for (int j = 0; j < 3; j++) {
                double acc = 0;
                for (int k = 0; k < 3; k++) acc += H[k][i] * H[k][j];
                A[i][j] = acc;
            }
        for (int sweep = 0; sweep < 30; sweep++) {
            double off = fabs(A[0][1]) + fabs(A[0][2]) + fabs(A[1][2]);
            if (off < 1e-30) break;
            for (int pair = 0; pair < 3; pair++) {
                int p = (pair == 2) ? 1 : 0;
                int q = (pair == 0) ? 1 : 2;
                double apq = A[p][q];
                if (fabs(apq) < 1e-300) continue;
                double theta = (A[q][q] - A[p][p]) / (2.0 * apq);
                double tt = ((theta >= 0) ? 1.0 : -1.0) / (fabs(theta) + sqrt(theta * theta + 1.0));
                double cc = 1.0 / sqrt(tt * tt + 1.0);
                double ssn = tt * cc;
                for (int k = 0; k < 3; k++) {
                    double akp = A[k][p], akq = A[k][q];
                    A[k][p] = cc * akp - ssn * akq;
                    A[k][q] = ssn * akp + cc * akq;
                }
                for (int k = 0; k < 3; k++) {
                    double apk = A[p][k], aqk = A[q][k];
                    A[p][k] = cc * apk - ssn * aqk;
                    A[q][k] = ssn * apk + cc * aqk;
                }
                for (int k = 0; k < 3; k++) {
                    double vkp = Vv[k][p], vkq = Vv[k][q];
                    Vv[k][p] = cc * vkp - ssn * vkq;
                    Vv[k][q] = ssn * vkp + cc * vkq;
                }
            }
        }
        double wv[3] = {A[0][0], A[1][1], A[2][2]};
        for (int a = 0; a < 2; a++)
            for (int b2 = a + 1; b2 < 3; b2++)
                if (wv[b2] > wv[a]) {
                    double tw = wv[a]; wv[a] = wv[b2]; wv[b2] = tw;
                    for (int k = 0; k < 3; k++) {
                        double tv_ = Vv[k][a]; Vv[k][a] = Vv[k][b2]; Vv[k][b2] = tv_;
                    }
                }
        double U[3][3];
        for (int k = 0; k < 3; k++) {
            double u[3], nrm = 0;
            for (int i = 0; i < 3; i++) {
                double acc = 0;
                for (int j = 0; j < 3; j++) acc += H[i][j] * Vv[j][k];
                u[i] = acc; nrm += acc * acc;
            }
            nrm = sqrt(nrm);
            if (nrm < 1e-300) nrm = 1e-300;
            for (int i = 0; i < 3; i++) U[i][k] = u[i] / nrm;
        }
        double r[3][3];
        for (int i = 0; i < 3; i++)
            for (int j = 0; j < 3; j++) {
                double acc = 0;
                for (int k = 0; k < 3; k++) acc += Vv[i][k] * U[j][k];
                r[i][j] = acc;
            }
        double det = r[0][0] * (r[1][1] * r[2][2] - r[1][2] * r[2][1])
                   - r[0][1] * (r[1][0] * r[2][2] - r[1][2] * r[2][0])
                   + r[0][2] * (r[1][0] * r[2][1] - r[1][1] * r[2][0]);
        if (det < 0.0) {
            for (int i = 0; i < 3; i++)
                for (int j = 0; j < 3; j++)
                    r[i][j] -= 2.0 * Vv[i][2] * U[j][2];
        }
        double smean[3] = {(double)res[0], (double)res[1], (double)res[2]};
        double cmean[3] = {(double)res[3], (double)res[4], (double)res[5]};
        for (int i = 0; i < 3; i++)
            for (int j = 0; j < 3; j++)
                out[b * 9 + i * 3 + j] = (float)r[i][j];
        for (int i = 0; i < 3; i++) {
            double acc = cmean[i];
            for (int j = 0; j < 3; j++) acc -= r[i][j] * smean[j];
            out[B_ * 9 + b * 3 + i] = (float)acc;
        }
    }
}

// ---------------------------------------------------------------------------
extern "C" void kernel_launch(void* const* d_in, const int* in_sizes, int n_in,
                              void* d_out, int out_size, void* d_ws, size_t ws_size,
                              hipStream_t stream)
{
    const float* srcE = (const float*)d_in[0];
    const float* tgtE = (const float*)d_in[1];
    const float* src  = (const float*)d_in[2];
    const float* tgt  = (const float*)d_in[3];
    float* out = (float*)d_out;
    char* ws = (char*)d_ws;

    const size_t szP  = (size_t)B_ * N_ * KP * sizeof(u16);   // 64 MiB each
    const size_t szE8 = (size_t)B_ * N_ * N_;                 // 64 MiB fp8
    const size_t szStats = (size_t)B_ * N_ * sizeof(float)
                         + (size_t)B_ * N_ * TOPK * sizeof(float)
                         + (size_t)B_ * N_ * TOPK * sizeof(int)
                         + (size_t)B_ * N_ * sizeof(float)
                         + 2048;
    const bool fat = ws_size >= 2 * szP + szE8 + szStats;     // 196.3 MiB (proven)

    u16* srcP = (u16*)ws;
    u16* tgtP = (u16*)(ws + szP);
    unsigned char* e8 = fat ? (unsigned char*)(ws + 2 * szP) : nullptr;
    size_t off = 2 * szP + (fat ? szE8 : 0);
    float* rzbuf  = (float*)(ws + off); off += (size_t)B_ * N_ * sizeof(float);
    float* topv   = (float*)(ws + off); off += (size_t)B_ * N_ * TOPK * sizeof(float);
    int*   topc   = (int*)(ws + off);   off += (size_t)B_ * N_ * TOPK * sizeof(int);
    float* colsum = (float*)(ws + off); off += (size_t)B_ * N_ * sizeof(float);
    int*   mrow   = (int*)(ws + off);   off += 1024;
    int*   mcol   = (int*)(ws + off);

    hipMemsetAsync(colsum, 0, (size_t)B_ * N_ * sizeof(float), stream);

    packbf<<<dim3(N_ / 64, D_ / 64, 2 * B_), 256, 0, stream>>>(srcE, tgtE, srcP, tgtP);
    gemm7<<<dim3(256), 512, 0, stream>>>(srcP, tgtP, rzbuf, topv, topc, e8);
    if (fat)
        colsum3<<<dim3(2, 16, 16), 256, 0, stream>>>(e8, rzbuf, colsum);
    else
        gemm8<<<dim3(512), 512, 0, stream>>>(srcP, tgtP, rzbuf, colsum);
    match2<<<B_, 256, 0, stream>>>(topv, topc, mrow, mcol);
    finish_kernel<<<B_, 256, 0, stream>>>(src, tgt, colsum, mrow, mcol, out);
}

// Round 7
// 722.529 us; speedup vs baseline: 1.1126x; 1.0013x over previous
//
#include <hip/hip_runtime.h>
#include <hip/hip_fp16.h>
#include <math.h>

typedef unsigned short u16;
typedef __attribute__((ext_vector_type(8))) short bf16x8;   // 8 bf16 = 4 VGPR
typedef __attribute__((ext_vector_type(4))) float f32x4;

constexpr int B_ = 16;
constexpr int D_ = 512;
constexpr int N_ = 2048;
constexpr int S_ = 15;
constexpr int TOPK = 16;

constexpr int BK  = 32;
constexpr int KP  = 2 * D_;           // 1024 packed bf16 per row (hi|lo)
constexpr int BN7 = 256;              // chunk width
constexpr int SCW4 = 68;              // sC row stride for 64-col quarter
constexpr int SBUF = 24576;           // u16 per staging buffer (48 KB)

// async global->LDS, 16 bytes per lane (dest = wave-uniform base + lane*16)
__device__ __forceinline__ void gl_lds16(const void* g, void* s) {
    __builtin_amdgcn_global_load_lds(
        (const __attribute__((address_space(1))) unsigned int*)g,
        (__attribute__((address_space(3))) unsigned int*)s, 16, 0, 0);
}

// fp8 e4m3fn encode of a POSITIVE float (we only encode exp(l) > 0).
__device__ __forceinline__ unsigned enc1(float x) {
    x = fminf(x, 448.f);
    unsigned u = __float_as_uint(x);
    if (u < 0x3C800000u) return 0u;                    // < 2^-6
    unsigned r = u + 0x7FFFFu + ((u >> 20) & 1u);      // rn-even, keep 3 mant bits
    unsigned f = (r >> 20) - 0x3C0u;                   // rebias 127->7
    return f > 0x7Eu ? 0x7Eu : f;
}
__device__ __forceinline__ float dec1(unsigned f) {
    return f ? __uint_as_float((f + 0x3C0u) << 20) : 0.f;
}

// ---------------------------------------------------------------------------
// Pack: fp32 [B][D][N] -> bf16 hi/lo in STAGED-IMAGE order, so every gemm
// staging instruction reads a contiguous 1 KB run (base + lane*16B).
//   A-image (srcP): [b*16+panel]<<18 | kt<<14 | sec<<13 | w<<10 | l<<4
//   B-image (tgtP): [b]<<22 | chunk<<19 | kt<<15 | sec<<14 | hp<<13 | w<<10 | l<<4
// where panel = n/128, w = (n%128)/16, l = (n%16)*4 + physslot,
// physslot = s ^ (((n%16)>>1)&3)  (XOR swizzle baked in; s = k-slot of 8).
// ---------------------------------------------------------------------------
__global__ __launch_bounds__(256) void packbf(
    const float* __restrict__ srcE, const float* __restrict__ tgtE,
    u16* __restrict__ srcP, u16* __restrict__ tgtP)
{
    const int t = threadIdx.x;
    const int b = blockIdx.z & 15, sel = blockIdx.z >> 4;
    const float* in = (sel ? tgtE : srcE) + (size_t)b * D_ * N_;
    const int n0 = blockIdx.x * 64, k0 = blockIdx.y * 64;

    __shared__ float T[64][69];   // [k][n], stride 69 (odd*4B: spreads banks)

    #pragma unroll
    for (int it = 0; it < 4; it++) {
        int r = it * 16 + (t >> 4);           // k-row
        int c = (t & 15) * 4;                 // n-col
        float4 v = *(const float4*)&in[(size_t)(k0 + r) * N_ + n0 + c];
        T[r][c + 0] = v.x; T[r][c + 1] = v.y; T[r][c + 2] = v.z; T[r][c + 3] = v.w;
    }
    __syncthreads();

    const int tg = t & 127, kt_i = t >> 7;
    const int panel = n0 >> 7, wb = (n0 & 127) >> 4;
    const int kt = (k0 >> 5) + kt_i;
    char* outA = (char*)srcP;
    char* outB = (char*)tgtP;

    #pragma unroll
    for (int rep = 0; rep < 2; rep++) {
        const int g = rep * 128 + tg;
        const int wi = g >> 6, l = g & 63;
        const int w = wb + wi;
        const int s = (l & 3) ^ ((l >> 3) & 3);     // logical k-slot at phys l&3
        const int n_loc = wi * 16 + (l >> 2);
        const int kb = kt_i * 32 + s * 8;
        __align__(16) u16 hi[8], lo[8];
        #pragma unroll
        for (int j = 0; j < 8; j++) {
            float x = T[kb + j][n_loc];
            unsigned u = __float_as_uint(x);
            unsigned hr = u + 0x7fff + ((u >> 16) & 1);
            u16 h = (u16)(hr >> 16);
            float hf = __uint_as_float((unsigned)h << 16);
            float xl = x - hf;
            unsigned ul = __float_as_uint(xl);
            unsigned lr = ul + 0x7fff + ((ul >> 16) & 1);
            hi[j] = h; lo[j] = (u16)(lr >> 16);
        }
        if (!sel) {
            size_t base = (((size_t)(b * 16 + panel)) << 18) + ((size_t)kt << 14)
                        + ((size_t)w << 10) + ((size_t)l << 4);
            *(int4*)(outA + base)        = *(int4*)hi;   // sec=0 (hi)
            *(int4*)(outA + base + 8192) = *(int4*)lo;   // sec=1 (lo)
        } else {
            size_t base = ((size_t)b << 22) + ((size_t)(panel >> 1) << 19)
                        + ((size_t)kt << 15) + ((size_t)(panel & 1) << 13)
                        + ((size_t)w << 10) + ((size_t)l << 4);
            *(int4*)(outB + base)         = *(int4*)hi;  // sec=0 (Bh)
            *(int4*)(outB + base + 16384) = *(int4*)lo;  // sec=1 (Bl)
        }
    }
}

// ---------------------------------------------------------------------------
// Pass 1: MFMA GEMM -> 1/Z + sorted top-16 (l - logZ), fp8 E dump.
// Grid 256 (16 rowblocks x 16 batches, XCD-chunked), 512 threads.
// Merged k-step (16 steps/chunk, full {Ah,Al,Bh,Bl} 48 KB tile, 48 MFMA/wave),
// r4-proven __syncthreads 2-phase sync. Staging now reads the pre-tiled
// image: 6 gl_lds/wave, each a contiguous 1 KB (full 128B lines).
// LDS image and all read addressing identical to round 6.
// ---------------------------------------------------------------------------
__global__ __launch_bounds__(512, 2) void gemm7(
    const u16* __restrict__ srcP, const u16* __restrict__ tgtP,
    float* __restrict__ rzbuf, float* __restrict__ topv, int* __restrict__ topc,
    unsigned char* __restrict__ e8)       // nullptr -> no dump (thin path)
{
    __shared__ __align__(16) u16 sS[2 * SBUF];         // 96 KB staging (2 bufs)
    __shared__ __align__(16) float sC[128 * SCW4];     // 34 KB epilogue quarter

    const int tid = threadIdx.x;
    const int w = tid >> 6, lane = tid & 63;
    const int wr = w >> 2, wc = w & 3;
    const int sr = lane >> 2, q = lane & 3;
    const int bid = blockIdx.x;
    const int swz = (bid & 7) * 32 + (bid >> 3);
    const int b  = swz >> 4;
    const int s0 = (swz & 15) * 128;
    const float scale = 0.044194173824159216f;
    const int l16 = lane * 16;

    const char* aimg = (const char*)srcP + (((size_t)(b * 16 + (s0 >> 7))) << 18);
    const char* bimg = (const char*)tgtP + ((size_t)b << 22);

    // fragment read: row = 16i + (l&15), phys slot = (l>>4) ^ ((l>>1)&3)
    const int aro = (lane & 15) * BK + (((lane >> 4) ^ ((lane >> 1) & 3)) * 8);

    // stage step (kt, chunk): A 16 KB + B 32 KB, all contiguous 1 KB instrs
    auto stage = [&](int bi, int kt, int ch) {
        u16* base = &sS[bi * SBUF];
        const char* astep = aimg + ((size_t)kt << 14);
        const char* bstep = bimg + ((size_t)ch << 19) + ((size_t)kt << 15);
        #pragma unroll
        for (int j = 0; j < 2; j++)
            gl_lds16(astep + ((w * 2 + j) << 10) + l16, base + (w * 2 + j) * 512);
        #pragma unroll
        for (int j = 0; j < 4; j++)
            gl_lds16(bstep + ((w * 4 + j) << 10) + l16, base + 8192 + (w * 4 + j) * 512);
    };

    float z_loc = 0.f;
    float tv[TOPK]; int tc16[TOPK];
    #pragma unroll
    for (int k = 0; k < TOPK; k++) { tv[k] = -1e30f; tc16[k] = 0x7fffffff; }

    stage(0, 0, 0);

    for (int ch = 0; ch < 8; ch++) {
        const int c0 = ch * BN7;
        f32x4 acc[4][4];
        #pragma unroll
        for (int i = 0; i < 4; i++)
            #pragma unroll
            for (int j = 0; j < 4; j++) acc[i][j] = (f32x4){0.f, 0.f, 0.f, 0.f};

        for (int kt = 0; kt < 16; kt++) {
            __syncthreads();   // buf (kt&1) staged (vmcnt drained) & prev reads done
            if (kt < 15)      stage((kt + 1) & 1, kt + 1, ch);
            else if (ch < 7)  stage(0, 0, ch + 1);
            const u16* base = &sS[(kt & 1) * SBUF];
            bf16x8 ah[4], bh[4], tf[4];
            #pragma unroll
            for (int j = 0; j < 4; j++)
                bh[j] = *(const bf16x8*)&base[8192 + wc * 2048 + j * 512 + aro];
            #pragma unroll
            for (int i = 0; i < 4; i++)
                ah[i] = *(const bf16x8*)&base[wr * 2048 + i * 512 + aro];
            #pragma unroll
            for (int i = 0; i < 4; i++)
                #pragma unroll
                for (int j = 0; j < 4; j++)
                    acc[i][j] = __builtin_amdgcn_mfma_f32_16x16x32_bf16(
                        ah[i], bh[j], acc[i][j], 0, 0, 0);
            #pragma unroll
            for (int i = 0; i < 4; i++)
                tf[i] = *(const bf16x8*)&base[4096 + wr * 2048 + i * 512 + aro];
            #pragma unroll
            for (int i = 0; i < 4; i++)
                #pragma unroll
                for (int j = 0; j < 4; j++)
                    acc[i][j] = __builtin_amdgcn_mfma_f32_16x16x32_bf16(
                        tf[i], bh[j], acc[i][j], 0, 0, 0);
            #pragma unroll
            for (int j = 0; j < 4; j++)
                tf[j] = *(const bf16x8*)&base[16384 + wc * 2048 + j * 512 + aro];
            #pragma unroll
            for (int i = 0; i < 4; i++)
                #pragma unroll
                for (int j = 0; j < 4; j++)
                    acc[i][j] = __builtin_amdgcn_mfma_f32_16x16x32_bf16(
                        ah[i], tf[j], acc[i][j], 0, 0, 0);
        }

        // ---- epilogue: 4 quarters of 64 cols through sC (lgkm-only barriers;
        // in-flight next-chunk stage loads are NOT drained here; e8 stores
        // are fire-and-forget and drain at the next k-loop __syncthreads) ----
        #pragma unroll 1
        for (int h = 0; h < 4; h++) {
            asm volatile("s_waitcnt lgkmcnt(0)" ::: "memory");  // prev reads retired
            __builtin_amdgcn_s_barrier();                        // sC free
            if (wc == h) {
                #pragma unroll
                for (int i = 0; i < 4; i++)
                    #pragma unroll
                    for (int j = 0; j < 4; j++)
                        #pragma unroll
                        for (int r = 0; r < 4; r++)
                            sC[(wr * 64 + i * 16 + (lane >> 4) * 4 + r) * SCW4
                               + j * 16 + (lane & 15)] = acc[i][j][r] * scale;
            }
            asm volatile("s_waitcnt lgkmcnt(0)" ::: "memory");  // writes complete
            __builtin_amdgcn_s_barrier();                        // sC filled
            const float* rowp = &sC[(w * 16 + sr) * SCW4 + q * 16];
            const int cbase = c0 + h * 64 + q * 16;
            unsigned ow0 = 0, ow1 = 0, ow2 = 0, ow3 = 0;
            #pragma unroll
            for (int mi = 0; mi < 4; mi++) {
                float4 v4 = *(const float4*)&rowp[mi * 4];
                const float vv[4] = {v4.x, v4.y, v4.z, v4.w};
                unsigned wb2 = 0;
                #pragma unroll
                for (int e = 0; e < 4; e++) {
                    float v = vv[e];
                    float ex = __expf(v);
                    z_loc += ex;
                    wb2 |= enc1(ex) << (8 * e);
                    if (v > tv[15]) {       // sorted-desc insert, stable
                        const int c = cbase + mi * 4 + e;
                        #pragma unroll
                        for (int k = 15; k >= 1; k--) {
                            bool bk  = v > tv[k];
                            bool bk1 = v > tv[k - 1];
                            float sv = bk1 ? tv[k - 1] : v;
                            int   sc = bk1 ? tc16[k - 1] : c;
                            tv[k]   = bk ? sv : tv[k];
                            tc16[k] = bk ? sc : tc16[k];
                        }
                        if (v > tv[0]) { tv[0] = v; tc16[0] = c; }
                    }
                }
                if (mi == 0) ow0 = wb2; else if (mi == 1) ow1 = wb2;
                else if (mi == 2) ow2 = wb2; else ow3 = wb2;
            }
            if (e8) {
                const size_t erow = ((size_t)(b * N_ + s0 + w * 16 + sr)) * N_ + cbase;
                *(uint4*)&e8[erow] = make_uint4(ow0, ow1, ow2, ow3);
            }
        }
    }

    // ---- final merge: wave-private slice in (now dead) staging LDS ----
    float* sCw = (float*)sS + w * 2112;
    int*   cbw = (int*)sCw;
    float* vbw = sCw + 1024;
    float* zqw = sCw + 2048;
    zqw[lane] = z_loc;
    #pragma unroll
    for (int k = 0; k < TOPK; k++) {
        vbw[lane * 16 + k] = tv[k];
        cbw[lane * 16 + k] = tc16[k];
    }
    if (q == 0) {
        float Z = zqw[lane] + zqw[lane + 1] + zqw[lane + 2] + zqw[lane + 3];
        float lz = logf(Z);
        const int grow = s0 + w * 16 + sr;
        rzbuf[b * N_ + grow] = 1.0f / Z;
        float tmin = -1e30f; int tminslot = 0, tmincol = 0x7fffffff;
        #pragma unroll
        for (int k = 0; k < TOPK; k++) { tv[k] = -1e30f; tc16[k] = 0x7fffffff; }
        for (int qq = 0; qq < 4; qq++) {
            #pragma unroll 1
            for (int k = 0; k < TOPK; k++) {
                float v = vbw[(lane + qq) * 16 + k];
                int c = cbw[(lane + qq) * 16 + k];
                bool ins = (v > tmin) || (v == tmin && c < tmincol);
                if (ins) {
                    #pragma unroll
                    for (int k2 = 0; k2 < TOPK; k2++)
                        if (k2 == tminslot) { tv[k2] = v; tc16[k2] = c; }
                    tmin = tv[0]; tmincol = tc16[0]; tminslot = 0;
                    #pragma unroll
                    for (int k2 = 1; k2 < TOPK; k2++) {
                        bool worse = (tv[k2] < tmin) || (tv[k2] == tmin && tc16[k2] > tmincol);
                        if (worse) { tmin = tv[k2]; tmincol = tc16[k2]; tminslot = k2; }
                    }
                }
            }
        }
        unsigned used = 0;
        size_t rowbase = ((size_t)b * N_ + grow) * TOPK;
        for (int o = 0; o < TOPK; o++) {
            float bvv = -1e31f; int bcc = 0x7fffffff; int bk = 0;
            #pragma unroll
            for (int k = 0; k < TOPK; k++) {
                bool u = (used >> k) & 1u;
                bool better = !u && ((tv[k] > bvv) || (tv[k] == bvv && tc16[k] < bcc));
                if (better) { bvv = tv[k]; bcc = tc16[k]; bk = k; }
            }
            used |= 1u << bk;
            topv[rowbase + o] = bvv - lz;
            topc[rowbase + o] = bcc;
        }
    }
}

// ---------------------------------------------------------------------------
// Fat path: colsum[b][t] = sum_s dec(E8[s][t]) * rz[s]. Grid (2,16,16), 256 thr.
// ---------------------------------------------------------------------------
__global__ __launch_bounds__(256) void colsum3(
    const unsigned char* __restrict__ e8, const float* __restrict__ rzbuf,
    float* __restrict__ colsum)
{
    const int b = blockIdx.z, s0 = blockIdx.y * 128, t0 = blockIdx.x * 1024;
    __shared__ float srz[128];
    if (threadIdx.x < 128) srz[threadIdx.x] = rzbuf[b * N_ + s0 + threadIdx.x];
    __syncthreads();
    const int t = t0 + threadIdx.x * 4;
    const unsigned char* p = e8 + ((size_t)(b * N_ + s0)) * N_ + t;
    float a0 = 0.f, a1 = 0.f, a2 = 0.f, a3 = 0.f;
    #pragma unroll 4
    for (int s = 0; s < 128; s++) {
        unsigned v = *(const unsigned*)(p + (size_t)s * N_);
        float r = srz[s];
        a0 += dec1(v & 255u) * r;
        a1 += dec1((v >> 8) & 255u) * r;
        a2 += dec1((v >> 16) & 255u) * r;
        a3 += dec1(v >> 24) * r;
    }
    atomicAdd(&colsum[b * N_ + t + 0], a0);
    atomicAdd(&colsum[b * N_ + t + 1], a1);
    atomicAdd(&colsum[b * N_ + t + 2], a2);
    atomicAdd(&colsum[b * N_ + t + 3], a3);
}

// ---------------------------------------------------------------------------
// Thin fallback (dormant; fat path proven): image-based GEMM recompute for
// colsum. Structural clone of gemm7's k-loop + register colsum epilogue.
// ---------------------------------------------------------------------------
__global__ __launch_bounds__(512, 2) void gemm8(
    const u16* __restrict__ srcP, const u16* __restrict__ tgtP,
    const float* __restrict__ rzbuf, float* __restrict__ colsum)
{
    __shared__ __align__(16) u16 sS[2 * SBUF];
    __shared__ float sRZ[128];

    const int tid = threadIdx.x;
    const int w = tid >> 6, lane = tid & 63;
    const int wr = w >> 2, wc = w & 3;
    const int bid = blockIdx.x;
    const int swz = (bid & 7) * 32 + (bid >> 3);
    const int b  = swz >> 4;
    const int s0 = (swz & 15) * 128;
    const float scale = 0.044194173824159216f;
    const int l16 = lane * 16;

    const char* aimg = (const char*)srcP + (((size_t)(b * 16 + (s0 >> 7))) << 18);
    const char* bimg = (const char*)tgtP + ((size_t)b << 22);
    const int aro = (lane & 15) * BK + (((lane >> 4) ^ ((lane >> 1) & 3)) * 8);

    if (tid < 128) sRZ[tid] = rzbuf[b * N_ + s0 + tid];

    auto stage = [&](int bi, int kt, int ch) {
        u16* base = &sS[bi * SBUF];
        const char* astep = aimg + ((size_t)kt << 14);
        const char* bstep = bimg + ((size_t)ch << 19) + ((size_t)kt << 15);
        #pragma unroll
        for (int j = 0; j < 2; j++)
            gl_lds16(astep + ((w * 2 + j) << 10) + l16, base + (w * 2 + j) * 512);
        #pragma unroll
        for (int j = 0; j < 4; j++)
            gl_lds16(bstep + ((w * 4 + j) << 10) + l16, base + 8192 + (w * 4 + j) * 512);
    };

    stage(0, 0, 0);

    for (int ch = 0; ch < 8; ch++) {
        const int c0 = ch * BN7;
        f32x4 acc[4][4];
        #pragma unroll
        for (int i = 0; i < 4; i++)
            #pragma unroll
            for (int j = 0; j < 4; j++) acc[i][j] = (f32x4){0.f, 0.f, 0.f, 0.f};

        for (int kt = 0; kt < 16; kt++) {
            __syncthreads();
            if (kt < 15)      stage((kt + 1) & 1, kt + 1, ch);
            else if (ch < 7)  stage(0, 0, ch + 1);
            const u16* base = &sS[(kt & 1) * SBUF];
            bf16x8 ah[4], bh[4], tf[4];
            #pragma unroll
            for (int j = 0; j < 4; j++)
                bh[j] = *(const bf16x8*)&base[8192 + wc * 2048 + j * 512 + aro];
            #pragma unroll
            for (int i = 0; i < 4; i++)
                ah[i] = *(const bf16x8*)&base[wr * 2048 + i * 512 + aro];
            #pragma unroll
            for (int i = 0; i < 4; i++)
                #pragma unroll
                for (int j = 0; j < 4; j++)
                    acc[i][j] = __builtin_amdgcn_mfma_f32_16x16x32_bf16(
                        ah[i], bh[j], acc[i][j], 0, 0, 0);
            #pragma unroll
            for (int i = 0; i < 4; i++)
                tf[i] = *(const bf16x8*)&base[4096 + wr * 2048 + i * 512 + aro];
            #pragma unroll
            for (int i = 0; i < 4; i++)
                #pragma unroll
                for (int j = 0; j < 4; j++)
                    acc[i][j] = __builtin_amdgcn_mfma_f32_16x16x32_bf16(
                        tf[i], bh[j], acc[i][j], 0, 0, 0);
            #pragma unroll
            for (int j = 0; j < 4; j++)
                tf[j] = *(const bf16x8*)&base[16384 + wc * 2048 + j * 512 + aro];
            #pragma unroll
            for (int i = 0; i < 4; i++)
                #pragma unroll
                for (int j = 0; j < 4; j++)
                    acc[i][j] = __builtin_amdgcn_mfma_f32_16x16x32_bf16(
                        ah[i], tf[j], acc[i][j], 0, 0, 0);
        }

        #pragma unroll
        for (int j = 0; j < 4; j++) {
            float s = 0.f;
            #pragma unroll
            for (int i = 0; i < 4; i++)
                #pragma unroll
                for (int r = 0; r < 4; r++)
                    s += __expf(acc[i][j][r] * scale)
                         * sRZ[wr * 64 + i * 16 + (lane >> 4) * 4 + r];
            s += __shfl_xor(s, 16);
            s += __shfl_xor(s, 32);
            if (lane < 16)
                atomicAdd(&colsum[b * N_ + c0 + wc * 64 + j * 16 + lane], s);
        }
    }
}

// ---------------------------------------------------------------------------
// Greedy match + finish (unchanged)
// ---------------------------------------------------------------------------
__global__ __launch_bounds__(256) void match2(
    const float* __restrict__ topv, const int* __restrict__ topc,
    int* __restrict__ mrow, int* __restrict__ mcol)
{
    const int b = blockIdx.x, tid = threadIdx.x;
    __shared__ float bv[N_];
    __shared__ int bc[N_];
    __shared__ int sup[16];
    __shared__ float rv[256];
    __shared__ int rr[256];

    for (int r = tid; r < N_; r += 256) {
        bv[r] = topv[((size_t)b * N_ + r) * TOPK];
        bc[r] = topc[((size_t)b * N_ + r) * TOPK];
    }
    __syncthreads();

    for (int it = 0; it < S_; it++) {
        float mv = -1e30f; int mr = 0x7fffffff;
        #pragma unroll
        for (int j = 0; j < 8; j++) {
            int r = tid + j * 256;
            float v = bv[r];
            if (v > mv) { mv = v; mr = r; }
        }
        rv[tid] = mv; rr[tid] = mr;
        __syncthreads();
        for (int off = 128; off; off >>= 1) {
            if (tid < off) {
                float v2 = rv[tid + off];
                if (v2 > rv[tid] || (v2 == rv[tid] && rr[tid + off] < rr[tid])) {
                    rv[tid] = v2; rr[tid] = rr[tid + off];
                }
            }
            __syncthreads();
        }
        if (tid == 0) {
            int R = rr[0]; int C = bc[R];
            mrow[b * S_ + it] = R; mcol[b * S_ + it] = C;
            sup[it] = C;
            bv[R] = -1e30f;
        }
        __syncthreads();
        const int C = sup[it];
        for (int r = tid; r < N_; r += 256) {
            if (bc[r] == C && bv[r] > -1e29f) {
                float nv = -1e30f; int nc = 0x7fffffff;
                const float* tvp = &topv[((size_t)b * N_ + r) * TOPK];
                const int* tcp = &topc[((size_t)b * N_ + r) * TOPK];
                for (int k = 0; k < TOPK; k++) {
                    int c2 = tcp[k];
                    bool bad = false;
                    for (int qq = 0; qq <= it; qq++) bad = bad || (sup[qq] == c2);
                    if (!bad) { nv = tvp[k]; nc = c2; break; }
                }
                bv[r] = nv; bc[r] = nc;
            }
        }
        __syncthreads();
    }
}

__global__ void finish_kernel(const float* __restrict__ src,
                              const float* __restrict__ tgt,
                              const float* __restrict__ colsum,
                              const int* __restrict__ mrow,
                              const int* __restrict__ mcol,
                              float* __restrict__ out)
{
    const int b = blockIdx.x;
    const int tid = threadIdx.x;
    __shared__ float red[256];
    __shared__ float res[6];

    float ls[3] = {0, 0, 0}, lc[3] = {0, 0, 0};
    for (int n = tid; n < N_; n += 256) {
        float cs = colsum[b * N_ + n];
        #pragma unroll
        for (int j = 0; j < 3; j++) {
            ls[j] += src[(size_t)(b * N_ + n) * 3 + j];
            lc[j] += tgt[(size_t)(b * N_ + n) * 3 + j] * cs;
        }
    }
    for (int j = 0; j < 6; j++) {
        red[tid] = (j < 3) ? ls[j] : lc[j - 3];
        __syncthreads();
        for (int off = 128; off; off >>= 1) {
            if (tid < off) red[tid] += red[tid + off];
            __syncthreads();
        }
        if (tid == 0) res[j] = red[0] / (float)N_;
        __syncthreads();
    }

    if (tid == 0) {
        double ps[S_][3], pt[S_][3];
        double ms[3] = {0, 0, 0}, mt[3] = {0, 0, 0};
        for (int s = 0; s < S_; s++) {
            int r = mrow[b * S_ + s], c = mcol[b * S_ + s];
            for (int j = 0; j < 3; j++) {
                ps[s][j] = (double)src[(size_t)(b * N_ + r) * 3 + j];
                pt[s][j] = (double)tgt[(size_t)(b * N_ + c) * 3 + j];
                ms[j] += ps[s][j]; mt[j] += pt[s][j];
            }
        }
        for (int j = 0; j < 3; j++) { ms[j] /= S_; mt[j] /= S_; }
        double H[3][3] = {{0,0,0},{0,0,0},{0,0,0}};
        for (int s = 0; s < S_; s++)
            for (int i = 0; i < 3; i++)
                for (int j = 0; j < 3; j++)
                    H[i][j] += (ps[s][i] - ms[i]) * (pt[s][j] - mt[j]);

        double A[3][3], Vv[3][3] = {{1,0,0},{0,1,0},{0,0,1}};
        for (int i = 0; i < 3; i++)
            for (int j = 0; j < 3; j++) {
                double acc = 0;
                for (int k = 0; k < 3; k++) acc += H[k][i] * H[k][j];
                A[i][j] = acc;
            }
        for (int sweep = 0; sweep < 30; sweep++) {
            double off = fabs(A[0][1]) + fabs(A[0][2]) + fabs(A[1][2]);
            if (off < 1e-30) break;
            for (int pair = 0; pair < 3; pair++) {
                int p = (pair == 2) ? 1 : 0;
                int q = (pair == 0) ? 1 : 2;
                double apq = A[p][q];
                if (fabs(apq) < 1e-300) continue;
                double theta = (A[q][q] - A[p][p]) / (2.0 * apq);
                double tt = ((theta >= 0) ? 1.0 : -1.0) / (fabs(theta) + sqrt(theta * theta + 1.0));
                double cc = 1.0 / sqrt(tt * tt + 1.0);
                double ssn = tt * cc;
                for (int k = 0; k < 3; k++) {
                    double akp = A[k][p], akq = A[k][q];
                    A[k][p] = cc * akp - ssn * akq;
                    A[k][q] = ssn * akp + cc * akq;
                }
                for (int k = 0; k < 3; k++) {
                    double apk = A[p][k], aqk = A[q][k];
                    A[p][k] = cc * apk - ssn * aqk;
                    A[q][k] = ssn * apk + cc * aqk;
                }
                for (int k = 0; k < 3; k++) {
                    double vkp = Vv[k][p], vkq = Vv[k][q];
                    Vv[k][p] = cc * vkp - ssn * vkq;
                    Vv[k][q] = ssn * vkp + cc * vkq;
                }
            }
        }
        double wv[3] = {A[0][0], A[1][1], A[2][2]};
        for (int a = 0; a < 2; a++)
            for (int b2 = a + 1; b2 < 3; b2++)
                if (wv[b2] > wv[a]) {
                    double tw = wv[a]; wv[a] = wv[b2]; wv[b2] = tw;
                    for (int k = 0; k < 3; k++) {
                        double tv_ = Vv[k][a]; Vv[k][a] = Vv[k][b2]; Vv[k][b2] = tv_;
                    }
                }
        double U[3][3];
        for (int k = 0; k < 3; k++) {
            double u[3], nrm = 0;
            for (int i = 0; i < 3; i++) {
                double acc = 0;
                for (int j = 0; j < 3; j++) acc += H[i][j] * Vv[j][k];
                u[i] = acc; nrm += acc * acc;
            }
            nrm = sqrt(nrm);
            if (nrm < 1e-300) nrm = 1e-300;
            for (int i = 0; i < 3; i++) U[i][k] = u[i] / nrm;
        }
        double r[3][3];
        for (int i = 0; i < 3; i++)
            for (int j = 0; j < 3; j++) {
                double acc = 0;
                for (int k = 0; k < 3; k++) acc += Vv[i][k] * U[j][k];
                r[i][j] = acc;
            }
        double det = r[0][0] * (r[1][1] * r[2][2] - r[1][2] * r[2][1])
                   - r[0][1] * (r[1][0] * r[2][2] - r[1][2] * r[2][0])
                   + r[0][2] * (r[1][0] * r[2][1] - r[1][1] * r[2][0]);
        if (det < 0.0) {
            for (int i = 0; i < 3; i++)
                for (int j = 0; j < 3; j++)
                    r[i][j] -= 2.0 * Vv[i][2] * U[j][2];
        }
        double smean[3] = {(double)res[0], (double)res[1], (double)res[2]};
        double cmean[3] = {(double)res[3], (double)res[4], (double)res[5]};
        for (int i = 0; i < 3; i++)
            for (int j = 0; j < 3; j++)
                out[b * 9 + i * 3 + j] = (float)r[i][j];
        for (int i = 0; i < 3; i++) {
            double acc = cmean[i];
            for (int j = 0; j < 3; j++) acc -= r[i][j] * smean[j];
            out[B_ * 9 + b * 3 + i] = (float)acc;
        }
    }
}

// ---------------------------------------------------------------------------
extern "C" void kernel_launch(void* const* d_in, const int* in_sizes, int n_in,
                              void* d_out, int out_size, void* d_ws, size_t ws_size,
                              hipStream_t stream)
{
    const float* srcE = (const float*)d_in[0];
    const float* tgtE = (const float*)d_in[1];
    const float* src  = (const float*)d_in[2];
    const float* tgt  = (const float*)d_in[3];
    float* out = (float*)d_out;
    char* ws = (char*)d_ws;

    const size_t szP  = (size_t)B_ * N_ * KP * sizeof(u16);   // 64 MiB each
    const size_t szE8 = (size_t)B_ * N_ * N_;                 // 64 MiB fp8
    const size_t szStats = (size_t)B_ * N_ * sizeof(float)
                         + (size_t)B_ * N_ * TOPK * sizeof(float)
                         + (size_t)B_ * N_ * TOPK * sizeof(int)
                         + (size_t)B_ * N_ * sizeof(float)
                         + 2048;
    const bool fat = ws_size >= 2 * szP + szE8 + szStats;     // 196.3 MiB (proven)

    u16* srcP = (u16*)ws;
    u16* tgtP = (u16*)(ws + szP);
    unsigned char* e8 = fat ? (unsigned char*)(ws + 2 * szP) : nullptr;
    size_t off = 2 * szP + (fat ? szE8 : 0);
    float* rzbuf  = (float*)(ws + off); off += (size_t)B_ * N_ * sizeof(float);
    float* topv   = (float*)(ws + off); off += (size_t)B_ * N_ * TOPK * sizeof(float);
    int*   topc   = (int*)(ws + off);   off += (size_t)B_ * N_ * TOPK * sizeof(int);
    float* colsum = (float*)(ws + off); off += (size_t)B_ * N_ * sizeof(float);
    int*   mrow   = (int*)(ws + off);   off += 1024;
    int*   mcol   = (int*)(ws + off);

    hipMemsetAsync(colsum, 0, (size_t)B_ * N_ * sizeof(float), stream);

    packbf<<<dim3(N_ / 64, D_ / 64, 2 * B_), 256, 0, stream>>>(srcE, tgtE, srcP, tgtP);
    gemm7<<<dim3(256), 512, 0, stream>>>(srcP, tgtP, rzbuf, topv, topc, e8);
    if (fat)
        colsum3<<<dim3(2, 16, 16), 256, 0, stream>>>(e8, rzbuf, colsum);
    else
        gemm8<<<dim3(256), 512, 0, stream>>>(srcP, tgtP, rzbuf, colsum);
    match2<<<B_, 256, 0, stream>>>(topv, topc, mrow, mcol);
    finish_kernel<<<B_, 256, 0, stream>>>(src, tgt, colsum, mrow, mcol, out);
}

// Round 8
// 633.984 us; speedup vs baseline: 1.2680x; 1.1397x over previous
//
#include <hip/hip_runtime.h>
#include <hip/hip_fp16.h>
#include <math.h>

typedef unsigned short u16;
typedef __attribute__((ext_vector_type(8))) short bf16x8;   // 8 bf16 = 4 VGPR
typedef __attribute__((ext_vector_type(4))) float f32x4;

constexpr int B_ = 16;
constexpr int D_ = 512;
constexpr int N_ = 2048;
constexpr int S_ = 15;
constexpr int TOPK = 16;

constexpr int BK  = 32;
constexpr int KP  = 2 * D_;           // 1024 packed bf16 per row (hi|lo)
constexpr int SB7 = 12288;            // u16 per gemm7 staging buffer (24 KB)
constexpr int SCW = 36;               // sC row stride (32 + 4)

// async global->LDS, 16 bytes per lane (dest = wave-uniform base + lane*16)
__device__ __forceinline__ void gl_lds16(const void* g, void* s) {
    __builtin_amdgcn_global_load_lds(
        (const __attribute__((address_space(1))) unsigned int*)g,
        (__attribute__((address_space(3))) unsigned int*)s, 16, 0, 0);
}

// fp8 e4m3fn encode of a POSITIVE float (we only encode exp(l) > 0).
__device__ __forceinline__ unsigned enc1(float x) {
    x = fminf(x, 448.f);
    unsigned u = __float_as_uint(x);
    if (u < 0x3C800000u) return 0u;                    // < 2^-6
    unsigned r = u + 0x7FFFFu + ((u >> 20) & 1u);      // rn-even, keep 3 mant bits
    unsigned f = (r >> 20) - 0x3C0u;                   // rebias 127->7
    return f > 0x7Eu ? 0x7Eu : f;
}
__device__ __forceinline__ float dec1(unsigned f) {
    return f ? __uint_as_float((f + 0x3C0u) << 20) : 0.f;
}

// ---------------------------------------------------------------------------
// Pack: fp32 [B][D][N] -> bf16 hi/lo in STAGED-IMAGE order (unchanged r7):
//   A-image (srcP): [b*16+panel]<<18 | kt<<14 | sec<<13 | w<<10 | l<<4
//   B-image (tgtP): [b]<<22 | c2<<19 | kt<<15 | sec<<14 | hp<<13 | w<<10 | l<<4
// panel = n/128, w = 16-col group, l = (n%16)*4 + physslot,
// physslot = s ^ (((n%16)>>1)&3)  (XOR swizzle baked in).
// ---------------------------------------------------------------------------
__global__ __launch_bounds__(256) void packbf(
    const float* __restrict__ srcE, const float* __restrict__ tgtE,
    u16* __restrict__ srcP, u16* __restrict__ tgtP)
{
    const int t = threadIdx.x;
    const int b = blockIdx.z & 15, sel = blockIdx.z >> 4;
    const float* in = (sel ? tgtE : srcE) + (size_t)b * D_ * N_;
    const int n0 = blockIdx.x * 64, k0 = blockIdx.y * 64;

    __shared__ float T[64][69];   // [k][n]

    #pragma unroll
    for (int it = 0; it < 4; it++) {
        int r = it * 16 + (t >> 4);           // k-row
        int c = (t & 15) * 4;                 // n-col
        float4 v = *(const float4*)&in[(size_t)(k0 + r) * N_ + n0 + c];
        T[r][c + 0] = v.x; T[r][c + 1] = v.y; T[r][c + 2] = v.z; T[r][c + 3] = v.w;
    }
    __syncthreads();

    const int tg = t & 127, kt_i = t >> 7;
    const int panel = n0 >> 7, wb = (n0 & 127) >> 4;
    const int kt = (k0 >> 5) + kt_i;
    char* outA = (char*)srcP;
    char* outB = (char*)tgtP;

    #pragma unroll
    for (int rep = 0; rep < 2; rep++) {
        const int g = rep * 128 + tg;
        const int wi = g >> 6, l = g & 63;
        const int w = wb + wi;
        const int s = (l & 3) ^ ((l >> 3) & 3);
        const int n_loc = wi * 16 + (l >> 2);
        const int kb = kt_i * 32 + s * 8;
        __align__(16) u16 hi[8], lo[8];
        #pragma unroll
        for (int j = 0; j < 8; j++) {
            float x = T[kb + j][n_loc];
            unsigned u = __float_as_uint(x);
            unsigned hr = u + 0x7fff + ((u >> 16) & 1);
            u16 h = (u16)(hr >> 16);
            float hf = __uint_as_float((unsigned)h << 16);
            float xl = x - hf;
            unsigned ul = __float_as_uint(xl);
            unsigned lr = ul + 0x7fff + ((ul >> 16) & 1);
            hi[j] = h; lo[j] = (u16)(lr >> 16);
        }
        if (!sel) {
            size_t base = (((size_t)(b * 16 + panel)) << 18) + ((size_t)kt << 14)
                        + ((size_t)w << 10) + ((size_t)l << 4);
            *(int4*)(outA + base)        = *(int4*)hi;
            *(int4*)(outA + base + 8192) = *(int4*)lo;
        } else {
            size_t base = ((size_t)b << 22) + ((size_t)(panel >> 1) << 19)
                        + ((size_t)kt << 15) + ((size_t)(panel & 1) << 13)
                        + ((size_t)w << 10) + ((size_t)l << 4);
            *(int4*)(outB + base)         = *(int4*)hi;
            *(int4*)(outB + base + 16384) = *(int4*)lo;
        }
    }
}

// ---------------------------------------------------------------------------
// Pass 1: MFMA GEMM -> 1/Z + sorted top-16 (l - logZ), fp8 E dump.
// Grid 512 (32 rowblocks x 16 batches, XCD-chunked), 512 threads.
// BM=64 x BN=128 tile, 8 waves of 32x32. 57 KB LDS -> 2 blocks/CU:
// one block's vmcnt-drain overlaps the sibling's MFMA/VALU (m114).
// K-step: {Ah,Al,Bh,Bl} 24 KB dbuf, proven __syncthreads 2-phase sync.
// Epilogue: 4 slices of 32 cols/chunk via sC; per-lane top16 (8 lanes/row);
// final 8-list merge in dead staging LDS.
// ---------------------------------------------------------------------------
__global__ __launch_bounds__(512, 4) void gemm7(
    const u16* __restrict__ srcP, const u16* __restrict__ tgtP,
    float* __restrict__ rzbuf, float* __restrict__ topv, int* __restrict__ topc,
    unsigned char* __restrict__ e8)       // nullptr -> no dump (thin path)
{
    __shared__ __align__(16) u16 sS[2 * SB7];        // 48 KB staging (2 bufs)
    __shared__ __align__(16) float sC[64 * SCW];     // 9 KB epilogue slice

    const int tid = threadIdx.x;
    const int w = tid >> 6, lane = tid & 63;
    const int wr = w >> 2, wc = w & 3;               // wave tile 32x32
    const int bid = blockIdx.x;
    const int swz = (bid & 7) * 64 + (bid >> 3);     // 8 XCD x 64: 2 batches/XCD
    const int b  = swz >> 5;
    const int s0 = (swz & 31) * 64;
    const float scale = 0.044194173824159216f;
    const int l16 = lane * 16;
    const int wb = (s0 & 127) >> 4;                  // A w-group base (0 or 4)

    const char* aimg = (const char*)srcP + (((size_t)(b * 16 + (s0 >> 7))) << 18);
    const char* bimg = (const char*)tgtP + ((size_t)b << 22);

    // fragment read: row = 16i + (l&15), phys slot = (l>>4) ^ ((l>>1)&3)
    const int aro = (lane & 15) * BK + (((lane >> 4) ^ ((lane >> 1) & 3)) * 8);

    // step buffer (u16): Ah [0,2048) | Al [2048,4096) | Bh [4096,8192) | Bl [8192,12288)
    auto stage = [&](int bi, int kt, int ch) {
        u16* base = &sS[bi * SB7];
        const char* astep = aimg + ((size_t)kt << 14);
        const char* bstep = bimg + ((size_t)(ch >> 1) << 19) + ((size_t)kt << 15)
                          + ((size_t)(ch & 1) << 13);
        const int sec = w >> 2;                       // 0: Ah, 1: Al
        gl_lds16(astep + (sec << 13) + ((wb + (w & 3)) << 10) + l16,
                 base + sec * 2048 + (w & 3) * 512);
        gl_lds16(bstep + (w << 10) + l16,          base + 4096 + w * 512);  // Bh
        gl_lds16(bstep + 16384 + (w << 10) + l16,  base + 8192 + w * 512);  // Bl
    };

    float z_loc = 0.f;
    float tv[TOPK]; int tc16[TOPK];
    #pragma unroll
    for (int k = 0; k < TOPK; k++) { tv[k] = -1e30f; tc16[k] = 0x7fffffff; }

    stage(0, 0, 0);

    for (int ch = 0; ch < 16; ch++) {
        f32x4 acc[2][2];
        #pragma unroll
        for (int i = 0; i < 2; i++)
            #pragma unroll
            for (int j = 0; j < 2; j++) acc[i][j] = (f32x4){0.f, 0.f, 0.f, 0.f};

        for (int kt = 0; kt < 16; kt++) {
            __syncthreads();   // buf (kt&1) staged (vmcnt drained) & prev reads done
            if (kt < 15)      stage((kt + 1) & 1, kt + 1, ch);
            else if (ch < 15) stage(0, 0, ch + 1);
            const u16* base = &sS[(kt & 1) * SB7];
            bf16x8 ah[2], bh[2], tf[2];
            #pragma unroll
            for (int j = 0; j < 2; j++)
                bh[j] = *(const bf16x8*)&base[4096 + (wc * 2 + j) * 512 + aro];
            #pragma unroll
            for (int i = 0; i < 2; i++)
                ah[i] = *(const bf16x8*)&base[(wr * 2 + i) * 512 + aro];
            #pragma unroll
            for (int i = 0; i < 2; i++)
                #pragma unroll
                for (int j = 0; j < 2; j++)
                    acc[i][j] = __builtin_amdgcn_mfma_f32_16x16x32_bf16(
                        ah[i], bh[j], acc[i][j], 0, 0, 0);
            #pragma unroll
            for (int i = 0; i < 2; i++)
                tf[i] = *(const bf16x8*)&base[2048 + (wr * 2 + i) * 512 + aro];
            #pragma unroll
            for (int i = 0; i < 2; i++)
                #pragma unroll
                for (int j = 0; j < 2; j++)
                    acc[i][j] = __builtin_amdgcn_mfma_f32_16x16x32_bf16(
                        tf[i], bh[j], acc[i][j], 0, 0, 0);
            #pragma unroll
            for (int j = 0; j < 2; j++)
                tf[j] = *(const bf16x8*)&base[8192 + (wc * 2 + j) * 512 + aro];
            #pragma unroll
            for (int i = 0; i < 2; i++)
                #pragma unroll
                for (int j = 0; j < 2; j++)
                    acc[i][j] = __builtin_amdgcn_mfma_f32_16x16x32_bf16(
                        ah[i], tf[j], acc[i][j], 0, 0, 0);
        }

        // ---- epilogue: 4 slices of 32 cols through sC (lgkm-only barriers;
        // next-chunk stage loads stay in flight; e8 stores drain at next
        // k-loop __syncthreads) ----
        #pragma unroll 1
        for (int h = 0; h < 4; h++) {
            asm volatile("s_waitcnt lgkmcnt(0)" ::: "memory");  // prev reads retired
            __builtin_amdgcn_s_barrier();                        // sC free
            if (wc == h) {   // 2 waves (wr=0,1) own these 32 cols
                #pragma unroll
                for (int i = 0; i < 2; i++)
                    #pragma unroll
                    for (int j = 0; j < 2; j++)
                        #pragma unroll
                        for (int r = 0; r < 4; r++)
                            sC[(wr * 32 + i * 16 + (lane >> 4) * 4 + r) * SCW
                               + j * 16 + (lane & 15)] = acc[i][j][r] * scale;
            }
            asm volatile("s_waitcnt lgkmcnt(0)" ::: "memory");  // writes complete
            __builtin_amdgcn_s_barrier();                        // sC filled
            // stats: row = w*8 + (lane>>3), cols (lane&7)*4 .. +3 (1 float4)
            const int row = w * 8 + (lane >> 3);
            float4 v4 = *(const float4*)&sC[row * SCW + (lane & 7) * 4];
            const float vv[4] = {v4.x, v4.y, v4.z, v4.w};
            const int cbase = ch * 128 + h * 32 + (lane & 7) * 4;
            unsigned wb2 = 0;
            #pragma unroll
            for (int e = 0; e < 4; e++) {
                float v = vv[e];
                float ex = __expf(v);
                z_loc += ex;
                wb2 |= enc1(ex) << (8 * e);
                if (v > tv[15]) {       // sorted-desc insert, stable
                    const int c = cbase + e;
                    #pragma unroll
                    for (int k = 15; k >= 1; k--) {
                        bool bk  = v > tv[k];
                        bool bk1 = v > tv[k - 1];
                        float sv = bk1 ? tv[k - 1] : v;
                        int   sc = bk1 ? tc16[k - 1] : c;
                        tv[k]   = bk ? sv : tv[k];
                        tc16[k] = bk ? sc : tc16[k];
                    }
                    if (v > tv[0]) { tv[0] = v; tc16[0] = c; }
                }
            }
            if (e8) {
                const size_t erow = ((size_t)(b * N_ + s0 + row)) * N_ + cbase;
                *(unsigned*)&e8[erow] = wb2;
            }
        }
    }

    // ---- final merge: 8 sorted lists per row (8 lanes/row). Per-wave region
    // in dead staging LDS: v[lane][16] f32 (4 KB) + c[lane][16] u16 (2 KB).
    float Z = z_loc;
    Z += __shfl_xor(Z, 1); Z += __shfl_xor(Z, 2); Z += __shfl_xor(Z, 4);
    float* vbw = (float*)((char*)sS + w * 6144);
    u16*   cbw = (u16*)((char*)sS + w * 6144 + 4096);
    __syncthreads();                     // staging dead; all k-loop reads done
    #pragma unroll
    for (int k = 0; k < TOPK; k++) {
        vbw[lane * 16 + k] = tv[k];
        cbw[lane * 16 + k] = (u16)tc16[k];
    }
    __syncthreads();
    if ((lane & 7) == 0) {
        const int grow = s0 + w * 8 + (lane >> 3);
        float lz = logf(Z);
        rzbuf[b * N_ + grow] = 1.0f / Z;
        float hv[8]; int hc[8]; int hix[8];
        #pragma unroll
        for (int m = 0; m < 8; m++) {
            hv[m] = vbw[(lane + m) * 16];
            hc[m] = cbw[(lane + m) * 16];
            hix[m] = 1;
        }
        size_t rowbase = ((size_t)b * N_ + grow) * TOPK;
        for (int o = 0; o < TOPK; o++) {
            float bv = hv[0]; int bc = hc[0]; int bm = 0;
            #pragma unroll
            for (int m = 1; m < 8; m++) {
                bool better = (hv[m] > bv) || (hv[m] == bv && hc[m] < bc);
                if (better) { bv = hv[m]; bc = hc[m]; bm = m; }
            }
            topv[rowbase + o] = bv - lz;
            topc[rowbase + o] = bc;
            int ni = 16;
            #pragma unroll
            for (int m = 0; m < 8; m++) if (m == bm) ni = hix[m];
            int rdi = ni < 15 ? ni : 15;
            float nv = vbw[(lane + bm) * 16 + rdi];
            int   nc = cbw[(lane + bm) * 16 + rdi];
            if (ni > 15) nv = -1e30f;
            #pragma unroll
            for (int m = 0; m < 8; m++)
                if (m == bm) { hv[m] = nv; hc[m] = nc; hix[m] = ni + 1; }
        }
    }
}

// ---------------------------------------------------------------------------
// Fat path: colsum[b][t] = sum_s dec(E8[s][t]) * rz[s]. Grid (2,16,16), 256 thr.
// ---------------------------------------------------------------------------
__global__ __launch_bounds__(256) void colsum3(
    const unsigned char* __restrict__ e8, const float* __restrict__ rzbuf,
    float* __restrict__ colsum)
{
    const int b = blockIdx.z, s0 = blockIdx.y * 128, t0 = blockIdx.x * 1024;
    __shared__ float srz[128];
    if (threadIdx.x < 128) srz[threadIdx.x] = rzbuf[b * N_ + s0 + threadIdx.x];
    __syncthreads();
    const int t = t0 + threadIdx.x * 4;
    const unsigned char* p = e8 + ((size_t)(b * N_ + s0)) * N_ + t;
    float a0 = 0.f, a1 = 0.f, a2 = 0.f, a3 = 0.f;
    #pragma unroll 4
    for (int s = 0; s < 128; s++) {
        unsigned v = *(const unsigned*)(p + (size_t)s * N_);
        float r = srz[s];
        a0 += dec1(v & 255u) * r;
        a1 += dec1((v >> 8) & 255u) * r;
        a2 += dec1((v >> 16) & 255u) * r;
        a3 += dec1(v >> 24) * r;
    }
    atomicAdd(&colsum[b * N_ + t + 0], a0);
    atomicAdd(&colsum[b * N_ + t + 1], a1);
    atomicAdd(&colsum[b * N_ + t + 2], a2);
    atomicAdd(&colsum[b * N_ + t + 3], a3);
}

// ---------------------------------------------------------------------------
// Thin fallback (dormant; fat path proven): r7 image-based GEMM recompute.
// ---------------------------------------------------------------------------
__global__ __launch_bounds__(512, 2) void gemm8(
    const u16* __restrict__ srcP, const u16* __restrict__ tgtP,
    const float* __restrict__ rzbuf, float* __restrict__ colsum)
{
    __shared__ __align__(16) u16 sS[2 * 24576];
    __shared__ float sRZ[128];

    const int tid = threadIdx.x;
    const int w = tid >> 6, lane = tid & 63;
    const int wr = w >> 2, wc = w & 3;
    const int bid = blockIdx.x;
    const int swz = (bid & 7) * 32 + (bid >> 3);
    const int b  = swz >> 4;
    const int s0 = (swz & 15) * 128;
    const float scale = 0.044194173824159216f;
    const int l16 = lane * 16;

    const char* aimg = (const char*)srcP + (((size_t)(b * 16 + (s0 >> 7))) << 18);
    const char* bimg = (const char*)tgtP + ((size_t)b << 22);
    const int aro = (lane & 15) * BK + (((lane >> 4) ^ ((lane >> 1) & 3)) * 8);

    if (tid < 128) sRZ[tid] = rzbuf[b * N_ + s0 + tid];

    auto stage = [&](int bi, int kt, int ch) {
        u16* base = &sS[bi * 24576];
        const char* astep = aimg + ((size_t)kt << 14);
        const char* bstep = bimg + ((size_t)ch << 19) + ((size_t)kt << 15);
        #pragma unroll
        for (int j = 0; j < 2; j++)
            gl_lds16(astep + ((w * 2 + j) << 10) + l16, base + (w * 2 + j) * 512);
        #pragma unroll
        for (int j = 0; j < 4; j++)
            gl_lds16(bstep + ((w * 4 + j) << 10) + l16, base + 8192 + (w * 4 + j) * 512);
    };

    stage(0, 0, 0);

    for (int ch = 0; ch < 8; ch++) {
        const int c0 = ch * 256;
        f32x4 acc[4][4];
        #pragma unroll
        for (int i = 0; i < 4; i++)
            #pragma unroll
            for (int j = 0; j < 4; j++) acc[i][j] = (f32x4){0.f, 0.f, 0.f, 0.f};

        for (int kt = 0; kt < 16; kt++) {
            __syncthreads();
            if (kt < 15)      stage((kt + 1) & 1, kt + 1, ch);
            else if (ch < 7)  stage(0, 0, ch + 1);
            const u16* base = &sS[(kt & 1) * 24576];
            bf16x8 ah[4], bh[4], tf[4];
            #pragma unroll
            for (int j = 0; j < 4; j++)
                bh[j] = *(const bf16x8*)&base[8192 + wc * 2048 + j * 512 + aro];
            #pragma unroll
            for (int i = 0; i < 4; i++)
                ah[i] = *(const bf16x8*)&base[wr * 2048 + i * 512 + aro];
            #pragma unroll
            for (int i = 0; i < 4; i++)
                #pragma unroll
                for (int j = 0; j < 4; j++)
                    acc[i][j] = __builtin_amdgcn_mfma_f32_16x16x32_bf16(
                        ah[i], bh[j], acc[i][j], 0, 0, 0);
            #pragma unroll
            for (int i = 0; i < 4; i++)
                tf[i] = *(const bf16x8*)&base[4096 + wr * 2048 + i * 512 + aro];
            #pragma unroll
            for (int i = 0; i < 4; i++)
                #pragma unroll
                for (int j = 0; j < 4; j++)
                    acc[i][j] = __builtin_amdgcn_mfma_f32_16x16x32_bf16(
                        tf[i], bh[j], acc[i][j], 0, 0, 0);
            #pragma unroll
            for (int j = 0; j < 4; j++)
                tf[j] = *(const bf16x8*)&base[16384 + wc * 2048 + j * 512 + aro];
            #pragma unroll
            for (int i = 0; i < 4; i++)
                #pragma unroll
                for (int j = 0; j < 4; j++)
                    acc[i][j] = __builtin_amdgcn_mfma_f32_16x16x32_bf16(
                        ah[i], tf[j], acc[i][j], 0, 0, 0);
        }

        #pragma unroll
        for (int j = 0; j < 4; j++) {
            float s = 0.f;
            #pragma unroll
            for (int i = 0; i < 4; i++)
                #pragma unroll
                for (int r = 0; r < 4; r++)
                    s += __expf(acc[i][j][r] * scale)
                         * sRZ[wr * 64 + i * 16 + (lane >> 4) * 4 + r];
            s += __shfl_xor(s, 16);
            s += __shfl_xor(s, 32);
            if (lane < 16)
                atomicAdd(&colsum[b * N_ + c0 + wc * 64 + j * 16 + lane], s);
        }
    }
}

// ---------------------------------------------------------------------------
// Greedy match + finish (unchanged)
// ---------------------------------------------------------------------------
__global__ __launch_bounds__(256) void match2(
    const float* __restrict__ topv, const int* __restrict__ topc,
    int* __restrict__ mrow, int* __restrict__ mcol)
{
    const int b = blockIdx.x, tid = threadIdx.x;
    __shared__ float bv[N_];
    __shared__ int bc[N_];
    __shared__ int sup[16];
    __shared__ float rv[256];
    __shared__ int rr[256];

    for (int r = tid; r < N_; r += 256) {
        bv[r] = topv[((size_t)b * N_ + r) * TOPK];
        bc[r] = topc[((size_t)b * N_ + r) * TOPK];
    }
    __syncthreads();

    for (int it = 0; it < S_; it++) {
        float mv = -1e30f; int mr = 0x7fffffff;
        #pragma unroll
        for (int j = 0; j < 8; j++) {
            int r = tid + j * 256;
            float v = bv[r];
            if (v > mv) { mv = v; mr = r; }
        }
        rv[tid] = mv; rr[tid] = mr;
        __syncthreads();
        for (int off = 128; off; off >>= 1) {
            if (tid < off) {
                float v2 = rv[tid + off];
                if (v2 > rv[tid] || (v2 == rv[tid] && rr[tid + off] < rr[tid])) {
                    rv[tid] = v2; rr[tid] = rr[tid + off];
                }
            }
            __syncthreads();
        }
        if (tid == 0) {
            int R = rr[0]; int C = bc[R];
            mrow[b * S_ + it] = R; mcol[b * S_ + it] = C;
            sup[it] = C;
            bv[R] = -1e30f;
        }
        __syncthreads();
        const int C = sup[it];
        for (int r = tid; r < N_; r += 256) {
            if (bc[r] == C && bv[r] > -1e29f) {
                float nv = -1e30f; int nc = 0x7fffffff;
                const float* tvp = &topv[((size_t)b * N_ + r) * TOPK];
                const int* tcp = &topc[((size_t)b * N_ + r) * TOPK];
                for (int k = 0; k < TOPK; k++) {
                    int c2 = tcp[k];
                    bool bad = false;
                    for (int qq = 0; qq <= it; qq++) bad = bad || (sup[qq] == c2);
                    if (!bad) { nv = tvp[k]; nc = c2; break; }
                }
                bv[r] = nv; bc[r] = nc;
            }
        }
        __syncthreads();
    }
}

__global__ void finish_kernel(const float* __restrict__ src,
                              const float* __restrict__ tgt,
                              const float* __restrict__ colsum,
                              const int* __restrict__ mrow,
                              const int* __restrict__ mcol,
                              float* __restrict__ out)
{
    const int b = blockIdx.x;
    const int tid = threadIdx.x;
    __shared__ float red[256];
    __shared__ float res[6];

    float ls[3] = {0, 0, 0}, lc[3] = {0, 0, 0};
    for (int n = tid; n < N_; n += 256) {
        float cs = colsum[b * N_ + n];
        #pragma unroll
        for (int j = 0; j < 3; j++) {
            ls[j] += src[(size_t)(b * N_ + n) * 3 + j];
            lc[j] += tgt[(size_t)(b * N_ + n) * 3 + j] * cs;
        }
    }
    for (int j = 0; j < 6; j++) {
        red[tid] = (j < 3) ? ls[j] : lc[j - 3];
        __syncthreads();
        for (int off = 128; off; off >>= 1) {
            if (tid < off) red[tid] += red[tid + off];
            __syncthreads();
        }
        if (tid == 0) res[j] = red[0] / (float)N_;
        __syncthreads();
    }

    if (tid == 0) {
        double ps[S_][3], pt[S_][3];
        double ms[3] = {0, 0, 0}, mt[3] = {0, 0, 0};
        for (int s = 0; s < S_; s++) {
            int r = mrow[b * S_ + s], c = mcol[b * S_ + s];
            for (int j = 0; j < 3; j++) {
                ps[s][j] = (double)src[(size_t)(b * N_ + r) * 3 + j];
                pt[s][j] = (double)tgt[(size_t)(b * N_ + c) * 3 + j];
                ms[j] += ps[s][j]; mt[j] += pt[s][j];
            }
        }
        for (int j = 0; j < 3; j++) { ms[j] /= S_; mt[j] /= S_; }
        double H[3][3] = {{0,0,0},{0,0,0},{0,0,0}};
        for (int s = 0; s < S_; s++)
            for (int i = 0; i < 3; i++)
                for (int j = 0; j < 3; j++)
                    H[i][j] += (ps[s][i] - ms[i]) * (pt[s][j] - mt[j]);

        double A[3][3], Vv[3][3] = {{1,0,0},{0,1,0},{0,0,1}};
        for (int i = 0; i < 3; i++)
            for (int j = 0; j < 3; j++) {
                double acc = 0;
                for (int k = 0; k < 3; k++) acc += H[k][i] * H[k][j];
                A[i][j] = acc;
            }
        for (int sweep = 0; sweep < 30; sweep++) {
            double off = fabs(A[0][1]) + fabs(A[0][2]) + fabs(A[1][2]);
            if (off < 1e-30) break;
            for (int pair = 0; pair < 3; pair++) {
                int p = (pair == 2) ? 1 : 0;
                int q = (pair == 0) ? 1 : 2;
                double apq = A[p][q];
                if (fabs(apq) < 1e-300) continue;
                double theta = (A[q][q] - A[p][p]) / (2.0 * apq);
                double tt = ((theta >= 0) ? 1.0 : -1.0) / (fabs(theta) + sqrt(theta * theta + 1.0));
                double cc = 1.0 / sqrt(tt * tt + 1.0);
                double ssn = tt * cc;
                for (int k = 0; k < 3; k++) {
                    double akp = A[k][p], akq = A[k][q];
                    A[k][p] = cc * akp - ssn * akq;
                    A[k][q] = ssn * akp + cc * akq;
                }
                for (int k = 0; k < 3; k++) {
                    double apk = A[p][k], aqk = A[q][k];
                    A[p][k] = cc * apk - ssn * aqk;
                    A[q][k] = ssn * apk + cc * aqk;
                }
                for (int k = 0; k < 3; k++) {
                    double vkp = Vv[k][p], vkq = Vv[k][q];
                    Vv[k][p] = cc * vkp - ssn * vkq;
                    Vv[k][q] = ssn * vkp + cc * vkq;
                }
            }
        }
        double wv[3] = {A[0][0], A[1][1], A[2][2]};
        for (int a = 0; a < 2; a++)
            for (int b2 = a + 1; b2 < 3; b2++)
                if (wv[b2] > wv[a]) {
                    double tw = wv[a]; wv[a] = wv[b2]; wv[b2] = tw;
                    for (int k = 0; k < 3; k++) {
                        double tv_ = Vv[k][a]; Vv[k][a] = Vv[k][b2]; Vv[k][b2] = tv_;
                    }
                }
        double U[3][3];
        for (int k = 0; k < 3; k++) {
            double u[3], nrm = 0;
            for (int i = 0; i < 3; i++) {
                double acc = 0;
                for (int j = 0; j < 3; j++) acc += H[i][j] * Vv[j][k];
                u[i] = acc; nrm += acc * acc;
            }
            nrm = sqrt(nrm);
            if (nrm < 1e-300) nrm = 1e-300;
            for (int i = 0; i < 3; i++) U[i][k] = u[i] / nrm;
        }
        double r[3][3];
        for (int i = 0; i < 3; i++)
            for (int j = 0; j < 3; j++) {
                double acc = 0;
                for (int k = 0; k < 3; k++) acc += Vv[i][k] * U[j][k];
                r[i][j] = acc;
            }
        double det = r[0][0] * (r[1][1] * r[2][2] - r[1][2] * r[2][1])
                   - r[0][1] * (r[1][0] * r[2][2] - r[1][2] * r[2][0])
                   + r[0][2] * (r[1][0] * r[2][1] - r[1][1] * r[2][0]);
        if (det < 0.0) {
            for (int i = 0; i < 3; i++)
                for (int j = 0; j < 3; j++)
                    r[i][j] -= 2.0 * Vv[i][2] * U[j][2];
        }
        double smean[3] = {(double)res[0], (double)res[1], (double)res[2]};
        double cmean[3] = {(double)res[3], (double)res[4], (double)res[5]};
        for (int i = 0; i < 3; i++)
            for (int j = 0; j < 3; j++)
                out[b * 9 + i * 3 + j] = (float)r[i][j];
        for (int i = 0; i < 3; i++) {
            double acc = cmean[i];
            for (int j = 0; j < 3; j++) acc -= r[i][j] * smean[j];
            out[B_ * 9 + b * 3 + i] = (float)acc;
        }
    }
}

// ---------------------------------------------------------------------------
extern "C" void kernel_launch(void* const* d_in, const int* in_sizes, int n_in,
                              void* d_out, int out_size, void* d_ws, size_t ws_size,
                              hipStream_t stream)
{
    const float* srcE = (const float*)d_in[0];
    const float* tgtE = (const float*)d_in[1];
    const float* src  = (const float*)d_in[2];
    const float* tgt  = (const float*)d_in[3];
    float* out = (float*)d_out;
    char* ws = (char*)d_ws;

    const size_t szP  = (size_t)B_ * N_ * KP * sizeof(u16);   // 64 MiB each
    const size_t szE8 = (size_t)B_ * N_ * N_;                 // 64 MiB fp8
    const size_t szStats = (size_t)B_ * N_ * sizeof(float)
                         + (size_t)B_ * N_ * TOPK * sizeof(float)
                         + (size_t)B_ * N_ * TOPK * sizeof(int)
                         + (size_t)B_ * N_ * sizeof(float)
                         + 2048;
    const bool fat = ws_size >= 2 * szP + szE8 + szStats;     // 196.3 MiB (proven)

    u16* srcP = (u16*)ws;
    u16* tgtP = (u16*)(ws + szP);
    unsigned char* e8 = fat ? (unsigned char*)(ws + 2 * szP) : nullptr;
    size_t off = 2 * szP + (fat ? szE8 : 0);
    float* rzbuf  = (float*)(ws + off); off += (size_t)B_ * N_ * sizeof(float);
    float* topv   = (float*)(ws + off); off += (size_t)B_ * N_ * TOPK * sizeof(float);
    int*   topc   = (int*)(ws + off);   off += (size_t)B_ * N_ * TOPK * sizeof(int);
    float* colsum = (float*)(ws + off); off += (size_t)B_ * N_ * sizeof(float);
    int*   mrow   = (int*)(ws + off);   off += 1024;
    int*   mcol   = (int*)(ws + off);

    hipMemsetAsync(colsum, 0, (size_t)B_ * N_ * sizeof(float), stream);

    packbf<<<dim3(N_ / 64, D_ / 64, 2 * B_), 256, 0, stream>>>(srcE, tgtE, srcP, tgtP);
    gemm7<<<dim3(512), 512, 0, stream>>>(srcP, tgtP, rzbuf, topv, topc, e8);
    if (fat)
        colsum3<<<dim3(2, 16, 16), 256, 0, stream>>>(e8, rzbuf, colsum);
    else
        gemm8<<<dim3(256), 512, 0, stream>>>(srcP, tgtP, rzbuf, colsum);
    match2<<<B_, 256, 0, stream>>>(topv, topc, mrow, mcol);
    finish_kernel<<<B_, 256, 0, stream>>>(src, tgt, colsum, mrow, mcol, out);
}